// Round 3
// baseline (579.606 us; speedup 1.0000x reference)
//
#include <hip/hip_runtime.h>

// ---- raw bf16 bits as unsigned short ----
typedef unsigned short bf16_t;
typedef unsigned short u16x8 __attribute__((ext_vector_type(8)));
typedef unsigned short u16x4 __attribute__((ext_vector_type(4)));
typedef float f32x4 __attribute__((ext_vector_type(4)));

#define D_MODEL 1024
#define NHEAD 16
#define DHEAD 64
#define FF_DIM 4096
#define SEQ 2048
#define BATCH 2

static __device__ __forceinline__ float bf2f(bf16_t b) {
  union { unsigned u; float f; } x;
  x.u = ((unsigned)b) << 16;
  return x.f;
}
static __device__ __forceinline__ bf16_t f2bf(float f) {
  union { float f; unsigned u; } x;
  x.f = f;
  unsigned r = (x.u + 0x7fffu + ((x.u >> 16) & 1u)) >> 16;
  return (bf16_t)r;
}

static __device__ __forceinline__ f32x4 mfma16(u16x8 a, u16x8 b, f32x4 c) {
  return __builtin_amdgcn_mfma_f32_16x16x32_bf16(a, b, c, 0, 0, 0);
}

// 8 contiguous fp32 -> 8 bf16 (two float4 loads, 16B-aligned callsites only)
static __device__ __forceinline__ u16x8 load8_f32(const float* q) {
  const float4 v0 = *(const float4*)(q);
  const float4 v1 = *(const float4*)(q + 4);
  u16x8 r;
  r[0] = f2bf(v0.x); r[1] = f2bf(v0.y); r[2] = f2bf(v0.z); r[3] = f2bf(v0.w);
  r[4] = f2bf(v1.x); r[5] = f2bf(v1.y); r[6] = f2bf(v1.z); r[7] = f2bf(v1.w);
  return r;
}

// ============================================================================
// GEMM: C[M,N] = act(A[M,K] @ W[N,K]^T + bias[N]);  W,bias fp32 inputs.
// A: fp32 (AF32=1) or internal bf16 (AF32=0). C: internal bf16.
// 128x128 tile, BK=32, 4 waves (2x2), wave = 64x64 = 4x4 frags of 16x16x32.
// SMODE: 0 = [M,N]; 1 = [B,H,S,DH] (Q/K); 2 = [B,H,DH,S] (V^T)
// ============================================================================
#define LDK 40  // padded LDS leading dim; 80B row stride keeps 16B alignment

template <int SMODE, int AF32>
__global__ __launch_bounds__(256) void gemm_bt(
    const void* __restrict__ A, const float* __restrict__ W,
    const float* __restrict__ bias, bf16_t* __restrict__ C,
    int M, int N, int K, int relu) {
  __shared__ bf16_t As[128 * LDK];
  __shared__ bf16_t Bs[128 * LDK];
  const int tid = threadIdx.x;
  const int lane = tid & 63;
  const int w = tid >> 6;
  const int wr = w >> 1, wc = w & 1;
  const int g = lane >> 4, c = lane & 15;
  const long bm = (long)blockIdx.y * 128;
  const long bn = (long)blockIdx.x * 128;

  f32x4 acc[4][4];
#pragma unroll
  for (int i = 0; i < 4; ++i)
#pragma unroll
    for (int j = 0; j < 4; ++j) acc[i][j] = (f32x4){0.f, 0.f, 0.f, 0.f};

  // staging: 128x32 tile = 512 chunks of 8; 256 threads x 2 chunks each
  const int r0 = tid >> 2, cc0 = (tid & 3) << 3;
  const int r1 = 64 + r0, cc1 = cc0;

  for (int k0 = 0; k0 < K; k0 += 32) {
    u16x8 a0, a1;
    if (AF32) {
      a0 = load8_f32((const float*)A + (bm + r0) * (long)K + k0 + cc0);
      a1 = load8_f32((const float*)A + (bm + r1) * (long)K + k0 + cc1);
    } else {
      a0 = *(const u16x8*)((const bf16_t*)A + (bm + r0) * (long)K + k0 + cc0);
      a1 = *(const u16x8*)((const bf16_t*)A + (bm + r1) * (long)K + k0 + cc1);
    }
    const u16x8 b0 = load8_f32(W + (bn + r0) * (long)K + k0 + cc0);
    const u16x8 b1 = load8_f32(W + (bn + r1) * (long)K + k0 + cc1);
    __syncthreads();  // previous iteration's LDS reads complete
    *(u16x8*)(As + r0 * LDK + cc0) = a0;
    *(u16x8*)(As + r1 * LDK + cc1) = a1;
    *(u16x8*)(Bs + r0 * LDK + cc0) = b0;
    *(u16x8*)(Bs + r1 * LDK + cc1) = b1;
    __syncthreads();
    u16x8 af[4], bfv[4];
#pragma unroll
    for (int i = 0; i < 4; ++i) {
      af[i] = *(const u16x8*)(As + (wr * 64 + i * 16 + c) * LDK + g * 8);
      bfv[i] = *(const u16x8*)(Bs + (wc * 64 + i * 16 + c) * LDK + g * 8);
    }
#pragma unroll
    for (int i = 0; i < 4; ++i)
#pragma unroll
      for (int j = 0; j < 4; ++j) acc[i][j] = mfma16(af[i], bfv[j], acc[i][j]);
  }

  // epilogue: D frag row=(lane>>4)*4+r, col=lane&15
#pragma unroll
  for (int i = 0; i < 4; ++i) {
#pragma unroll
    for (int j = 0; j < 4; ++j) {
      const int nn = (int)bn + wc * 64 + j * 16 + c;
      const float bv = bias[nn];
#pragma unroll
      for (int r = 0; r < 4; ++r) {
        const int mm = (int)bm + wr * 64 + i * 16 + g * 4 + r;
        float v = acc[i][j][r] + bv;
        if (relu) v = fmaxf(v, 0.f);
        const bf16_t o = f2bf(v);
        if (SMODE == 0) {
          C[(long)mm * N + nn] = o;
        } else if (SMODE == 1) {
          const int b = mm >> 11, s = mm & 2047, h = nn >> 6, dh = nn & 63;
          C[((((long)b * NHEAD + h) * SEQ + s) << 6) + dh] = o;
        } else {
          const int b = mm >> 11, s = mm & 2047, h = nn >> 6, dh = nn & 63;
          C[(((long)b * NHEAD + h) * DHEAD + dh) * SEQ + s] = o;
        }
      }
    }
  }
}

// ============================================================================
// Flash attention: Q,K [B*H, S, 64]; Vt [B*H, 64, S]; all internal bf16.
// 4 waves/block; each wave owns 16 Q rows, iterates K/V in 32-col tiles with
// online softmax. Output -> A1 [B*S, 1024] at column h*64.
// ============================================================================
__global__ __launch_bounds__(256) void attn_fwd(
    const bf16_t* __restrict__ Q, const bf16_t* __restrict__ K,
    const bf16_t* __restrict__ Vt, bf16_t* __restrict__ O) {
  __shared__ bf16_t P[4][16 * 32];
  const int tid = threadIdx.x;
  const int lane = tid & 63;
  const int w = tid >> 6;
  const int g = lane >> 4, c = lane & 15;
  const int bh = blockIdx.y;
  const int q0 = blockIdx.x * 64 + w * 16;
  const bf16_t* Qb = Q + (long)bh * SEQ * DHEAD;
  const bf16_t* Kb = K + (long)bh * SEQ * DHEAD;
  const bf16_t* Vb = Vt + (long)bh * DHEAD * SEQ;

  const u16x8 aq0 = *(const u16x8*)(Qb + (q0 + c) * DHEAD + g * 8);
  const u16x8 aq1 = *(const u16x8*)(Qb + (q0 + c) * DHEAD + 32 + g * 8);

  float m_r[4], l_r[4];
  f32x4 oacc[4];
#pragma unroll
  for (int r = 0; r < 4; ++r) { m_r[r] = -1e30f; l_r[r] = 0.f; }
#pragma unroll
  for (int d = 0; d < 4; ++d) oacc[d] = (f32x4){0.f, 0.f, 0.f, 0.f};

  for (int t0 = 0; t0 < SEQ; t0 += 32) {
    f32x4 s0 = (f32x4){0.f, 0.f, 0.f, 0.f};
    f32x4 s1 = s0;
    u16x8 bk;
    bk = *(const u16x8*)(Kb + (t0 + c) * DHEAD + g * 8);           s0 = mfma16(aq0, bk, s0);
    bk = *(const u16x8*)(Kb + (t0 + c) * DHEAD + 32 + g * 8);      s0 = mfma16(aq1, bk, s0);
    bk = *(const u16x8*)(Kb + (t0 + 16 + c) * DHEAD + g * 8);      s1 = mfma16(aq0, bk, s1);
    bk = *(const u16x8*)(Kb + (t0 + 16 + c) * DHEAD + 32 + g * 8); s1 = mfma16(aq1, bk, s1);

#pragma unroll
    for (int r = 0; r < 4; ++r) {
      const float a = s0[r] * 0.125f;   // 1/sqrt(64)
      const float b2 = s1[r] * 0.125f;
      float tm = fmaxf(a, b2);
      tm = fmaxf(tm, __shfl_xor(tm, 1));
      tm = fmaxf(tm, __shfl_xor(tm, 2));
      tm = fmaxf(tm, __shfl_xor(tm, 4));
      tm = fmaxf(tm, __shfl_xor(tm, 8));
      const float mn = fmaxf(m_r[r], tm);
      const float f = __expf(m_r[r] - mn);
      const float p0 = __expf(a - mn);
      const float p1 = __expf(b2 - mn);
      float ts = p0 + p1;
      ts += __shfl_xor(ts, 1);
      ts += __shfl_xor(ts, 2);
      ts += __shfl_xor(ts, 4);
      ts += __shfl_xor(ts, 8);
      l_r[r] = l_r[r] * f + ts;
      m_r[r] = mn;
#pragma unroll
      for (int d = 0; d < 4; ++d) oacc[d][r] *= f;
      P[w][(g * 4 + r) * 32 + c] = f2bf(p0);
      P[w][(g * 4 + r) * 32 + 16 + c] = f2bf(p1);
    }
    __syncthreads();
    const u16x8 pa = *(const u16x8*)(&P[w][c * 32 + g * 8]);
#pragma unroll
    for (int d = 0; d < 4; ++d) {
      const u16x8 bv = *(const u16x8*)(Vb + (long)(d * 16 + c) * SEQ + t0 + g * 8);
      oacc[d] = mfma16(pa, bv, oacc[d]);
    }
    __syncthreads();  // protect P before next tile's writes
  }

  const int b = bh >> 4, h = bh & 15;
#pragma unroll
  for (int r = 0; r < 4; ++r) {
    const float inv = 1.f / l_r[r];
    const long base = ((long)b * SEQ + q0 + g * 4 + r) * D_MODEL + h * DHEAD;
#pragma unroll
    for (int d = 0; d < 4; ++d) O[base + d * 16 + c] = f2bf(oacc[d][r] * inv);
  }
}

// ============================================================================
// Fused residual + LayerNorm: out = LN(X + Y)*gamma + beta.
// X: fp32 input (XF32=1) or internal bf16. Y: internal bf16.
// OUTF32=1 -> fp32 store (final output), else bf16 (internal X1).
// ============================================================================
template <int XF32, int OUTF32>
__global__ __launch_bounds__(256) void add_ln(
    const void* __restrict__ X, const bf16_t* __restrict__ Y,
    const float* __restrict__ gamma, const float* __restrict__ beta,
    void* __restrict__ Out) {
  __shared__ float red[2][4];
  const int tid = threadIdx.x;
  const int lane = tid & 63, w = tid >> 6;
  const long base = (long)blockIdx.x * D_MODEL;

  float xv[4];
  if (XF32) {
    const float4 t = *(const float4*)((const float*)X + base + tid * 4);
    xv[0] = t.x; xv[1] = t.y; xv[2] = t.z; xv[3] = t.w;
  } else {
    const u16x4 t = *(const u16x4*)((const bf16_t*)X + base + tid * 4);
#pragma unroll
    for (int i = 0; i < 4; ++i) xv[i] = bf2f(t[i]);
  }
  const u16x4 yv = *(const u16x4*)(Y + base + tid * 4);
  float v[4], s = 0.f, s2 = 0.f;
#pragma unroll
  for (int i = 0; i < 4; ++i) {
    const float t = xv[i] + bf2f(yv[i]);
    v[i] = t;
    s += t;
    s2 += t * t;
  }
#pragma unroll
  for (int off = 32; off; off >>= 1) {
    s += __shfl_xor(s, off);
    s2 += __shfl_xor(s2, off);
  }
  if (lane == 0) { red[0][w] = s; red[1][w] = s2; }
  __syncthreads();
  s = red[0][0] + red[0][1] + red[0][2] + red[0][3];
  s2 = red[1][0] + red[1][1] + red[1][2] + red[1][3];
  const float mu = s * (1.f / D_MODEL);
  const float var = s2 * (1.f / D_MODEL) - mu * mu;
  const float inv = rsqrtf(var + 1e-5f);
  const float4 gv = *(const float4*)(gamma + tid * 4);
  const float4 bv = *(const float4*)(beta + tid * 4);
  float o0 = (v[0] - mu) * inv * gv.x + bv.x;
  float o1 = (v[1] - mu) * inv * gv.y + bv.y;
  float o2 = (v[2] - mu) * inv * gv.z + bv.z;
  float o3 = (v[3] - mu) * inv * gv.w + bv.w;
  if (OUTF32) {
    float4 ov; ov.x = o0; ov.y = o1; ov.z = o2; ov.w = o3;
    *(float4*)((float*)Out + base + tid * 4) = ov;
  } else {
    u16x4 ov;
    ov[0] = f2bf(o0); ov[1] = f2bf(o1); ov[2] = f2bf(o2); ov[3] = f2bf(o3);
    *(u16x4*)((bf16_t*)Out + base + tid * 4) = ov;
  }
}

// ============================================================================
extern "C" void kernel_launch(void* const* d_in, const int* in_sizes, int n_in,
                              void* d_out, int out_size, void* d_ws, size_t ws_size,
                              hipStream_t stream) {
  const void*  src = d_in[0];
  const float* qw = (const float*)d_in[1];
  const float* qb = (const float*)d_in[2];
  const float* kw = (const float*)d_in[3];
  const float* kb = (const float*)d_in[4];
  const float* vw = (const float*)d_in[5];
  const float* vb = (const float*)d_in[6];
  const float* ow = (const float*)d_in[7];
  const float* ob = (const float*)d_in[8];
  const float* w1 = (const float*)d_in[9];
  const float* b1 = (const float*)d_in[10];
  const float* w2 = (const float*)d_in[11];
  const float* b2 = (const float*)d_in[12];
  const float* gam1 = (const float*)d_in[13];
  const float* bet1 = (const float*)d_in[14];
  const float* gam2 = (const float*)d_in[15];
  const float* bet2 = (const float*)d_in[16];

  char* ws = (char*)d_ws;
  const long MB = 1024 * 1024;
  bf16_t* Qw = (bf16_t*)(ws + 0 * MB);    // [B,H,S,DH]  8MB
  bf16_t* Kw = (bf16_t*)(ws + 8 * MB);    // [B,H,S,DH]  8MB
  bf16_t* Vt = (bf16_t*)(ws + 16 * MB);   // [B,H,DH,S]  8MB
  bf16_t* A1 = (bf16_t*)(ws + 24 * MB);   // attn out [M,1024] 8MB
  bf16_t* T1 = (bf16_t*)(ws + 32 * MB);   // o-proj / ff2 out  8MB
  bf16_t* X1 = (bf16_t*)(ws + 40 * MB);   // post-LN1          8MB
  bf16_t* F1 = (bf16_t*)(ws + 0 * MB);    // ff1 [M,4096] 32MB (reuses Q/K/V/A1)

  const int M = BATCH * SEQ;  // 4096
  dim3 blk(256);
  dim3 grid_n1024(1024 / 128, M / 128);
  dim3 grid_n4096(4096 / 128, M / 128);

  gemm_bt<1, 1><<<grid_n1024, blk, 0, stream>>>(src, qw, qb, Qw, M, 1024, 1024, 0);
  gemm_bt<1, 1><<<grid_n1024, blk, 0, stream>>>(src, kw, kb, Kw, M, 1024, 1024, 0);
  gemm_bt<2, 1><<<grid_n1024, blk, 0, stream>>>(src, vw, vb, Vt, M, 1024, 1024, 0);
  attn_fwd<<<dim3(SEQ / 64, BATCH * NHEAD), blk, 0, stream>>>(Qw, Kw, Vt, A1);
  gemm_bt<0, 0><<<grid_n1024, blk, 0, stream>>>(A1, ow, ob, T1, M, 1024, 1024, 0);
  add_ln<1, 0><<<dim3(M), blk, 0, stream>>>(src, T1, gam1, bet1, X1);
  gemm_bt<0, 0><<<grid_n4096, blk, 0, stream>>>(X1, w1, b1, F1, M, 4096, 1024, 1);
  gemm_bt<0, 0><<<grid_n1024, blk, 0, stream>>>(F1, w2, b2, T1, M, 1024, 4096, 0);
  add_ln<0, 1><<<dim3(M), blk, 0, stream>>>(X1, T1, gam2, bet2, d_out);
}

// Round 5
// 565.750 us; speedup vs baseline: 1.0245x; 1.0245x over previous
//
#include <hip/hip_runtime.h>

// ---- raw bf16 bits as unsigned short ----
typedef unsigned short bf16_t;
typedef unsigned short u16x8 __attribute__((ext_vector_type(8)));
typedef unsigned short u16x4 __attribute__((ext_vector_type(4)));
typedef float f32x4 __attribute__((ext_vector_type(4)));

#define D_MODEL 1024
#define NHEAD 16
#define DHEAD 64
#define FF_DIM 4096
#define SEQ 2048
#define BATCH 2
#define LOG2E 1.44269504088896340736f

#define EXP2F(x) __builtin_amdgcn_exp2f(x)

static __device__ __forceinline__ float bf2f(bf16_t b) {
  union { unsigned u; float f; } x;
  x.u = ((unsigned)b) << 16;
  return x.f;
}
static __device__ __forceinline__ bf16_t f2bf(float f) {
  union { float f; unsigned u; } x;
  x.f = f;
  unsigned r = (x.u + 0x7fffu + ((x.u >> 16) & 1u)) >> 16;
  return (bf16_t)r;
}
static __device__ __forceinline__ unsigned pack_bf16(float lo, float hi) {
  return (unsigned)f2bf(lo) | ((unsigned)f2bf(hi) << 16);
}

static __device__ __forceinline__ f32x4 mfma16(u16x8 a, u16x8 b, f32x4 c) {
  return __builtin_amdgcn_mfma_f32_16x16x32_bf16(a, b, c, 0, 0, 0);
}

// 8 contiguous fp32 -> 8 bf16 (two float4 loads; 16B-aligned callsites only)
static __device__ __forceinline__ u16x8 load8_f32(const float* q) {
  const float4 v0 = *(const float4*)(q);
  const float4 v1 = *(const float4*)(q + 4);
  u16x8 r;
  r[0] = f2bf(v0.x); r[1] = f2bf(v0.y); r[2] = f2bf(v0.z); r[3] = f2bf(v0.w);
  r[4] = f2bf(v1.x); r[5] = f2bf(v1.y); r[6] = f2bf(v1.z); r[7] = f2bf(v1.w);
  return r;
}

// ============================================================================
// fp32 -> bf16 bulk convert (n multiple of 2048)
// ============================================================================
__global__ __launch_bounds__(256) void cvt_f32_bf16(
    const float* __restrict__ in, bf16_t* __restrict__ out, long n) {
  const long i = ((long)blockIdx.x * 256 + threadIdx.x) * 8;
  if (i < n) *(u16x8*)(out + i) = load8_f32(in + i);
}

// ============================================================================
// GEMM: C[M,N] = act(A[M,K] @ W[N,K]^T + bias[N]) * oscale;  W,bias fp32.
// A: fp32 (AF32=1) or internal bf16 (AF32=0). C: internal bf16.
// 128x128 tile, BK=32, 4 waves (2x2), wave = 64x64 = 4x4 frags of 16x16x32.
// SMODE: 0 = [M,N]; 1 = [B,H,S,DH] (Q/K); 2 = [B,H,DH,S] (V^T)
// ============================================================================
#define LDK 40  // padded LDS leading dim; 80B row stride keeps 16B alignment

template <int SMODE, int AF32>
__global__ __launch_bounds__(256) void gemm_bt(
    const void* __restrict__ A, const float* __restrict__ W,
    const float* __restrict__ bias, bf16_t* __restrict__ C,
    int M, int N, int K, int relu, float oscale) {
  __shared__ bf16_t As[128 * LDK];
  __shared__ bf16_t Bs[128 * LDK];
  const int tid = threadIdx.x;
  const int lane = tid & 63;
  const int w = tid >> 6;
  const int wr = w >> 1, wc = w & 1;
  const int g = lane >> 4, c = lane & 15;
  const long bm = (long)blockIdx.y * 128;
  const long bn = (long)blockIdx.x * 128;

  f32x4 acc[4][4];
#pragma unroll
  for (int i = 0; i < 4; ++i)
#pragma unroll
    for (int j = 0; j < 4; ++j) acc[i][j] = (f32x4){0.f, 0.f, 0.f, 0.f};

  const int r0 = tid >> 2, cc0 = (tid & 3) << 3;
  const int r1 = 64 + r0, cc1 = cc0;

  for (int k0 = 0; k0 < K; k0 += 32) {
    u16x8 a0, a1;
    if (AF32) {
      a0 = load8_f32((const float*)A + (bm + r0) * (long)K + k0 + cc0);
      a1 = load8_f32((const float*)A + (bm + r1) * (long)K + k0 + cc1);
    } else {
      a0 = *(const u16x8*)((const bf16_t*)A + (bm + r0) * (long)K + k0 + cc0);
      a1 = *(const u16x8*)((const bf16_t*)A + (bm + r1) * (long)K + k0 + cc1);
    }
    const u16x8 b0 = load8_f32(W + (bn + r0) * (long)K + k0 + cc0);
    const u16x8 b1 = load8_f32(W + (bn + r1) * (long)K + k0 + cc1);
    __syncthreads();
    *(u16x8*)(As + r0 * LDK + cc0) = a0;
    *(u16x8*)(As + r1 * LDK + cc1) = a1;
    *(u16x8*)(Bs + r0 * LDK + cc0) = b0;
    *(u16x8*)(Bs + r1 * LDK + cc1) = b1;
    __syncthreads();
    u16x8 af[4], bfv[4];
#pragma unroll
    for (int i = 0; i < 4; ++i) {
      af[i] = *(const u16x8*)(As + (wr * 64 + i * 16 + c) * LDK + g * 8);
      bfv[i] = *(const u16x8*)(Bs + (wc * 64 + i * 16 + c) * LDK + g * 8);
    }
#pragma unroll
    for (int i = 0; i < 4; ++i)
#pragma unroll
      for (int j = 0; j < 4; ++j) acc[i][j] = mfma16(af[i], bfv[j], acc[i][j]);
  }

#pragma unroll
  for (int i = 0; i < 4; ++i) {
#pragma unroll
    for (int j = 0; j < 4; ++j) {
      const int nn = (int)bn + wc * 64 + j * 16 + c;
      const float bv = bias[nn];
#pragma unroll
      for (int r = 0; r < 4; ++r) {
        const int mm = (int)bm + wr * 64 + i * 16 + g * 4 + r;
        float v = (acc[i][j][r] + bv) * oscale;
        if (relu) v = fmaxf(v, 0.f);
        const bf16_t o = f2bf(v);
        if (SMODE == 0) {
          C[(long)mm * N + nn] = o;
        } else if (SMODE == 1) {
          const int b = mm >> 11, s = mm & 2047, h = nn >> 6, dh = nn & 63;
          C[((((long)b * NHEAD + h) * SEQ + s) << 6) + dh] = o;
        } else {
          const int b = mm >> 11, s = mm & 2047, h = nn >> 6, dh = nn & 63;
          C[(((long)b * NHEAD + h) * DHEAD + dh) * SEQ + s] = o;
        }
      }
    }
  }
}

// ============================================================================
// Flash attention, swapped-QK in-register softmax. Q pre-scaled by
// 0.125*log2e at projection, so softmax runs in exp2 domain.
// Q,K [B*H, S, 64]; Vt [B*H, 64, S]; all bf16. No LDS, no barriers.
// Per wave: 16 q rows. QK^T computed as mfma(K_rows, Q_rows) so each lane
// holds P[t=...][q=lane&15] -> softmax reduce = 2 shfl_xor over g.
// P repacked to bf16 + redistributed into PV A-frag via 8 shfl + cndmask.
// ============================================================================
__global__ __launch_bounds__(256) void attn_fwd(
    const bf16_t* __restrict__ Q, const bf16_t* __restrict__ K,
    const bf16_t* __restrict__ Vt, bf16_t* __restrict__ O) {
  const int tid = threadIdx.x;
  const int lane = tid & 63;
  const int w = tid >> 6;
  const int g = lane >> 4, c = lane & 15;
  const int bh = blockIdx.y;
  const int q0 = blockIdx.x * 64 + w * 16;
  const bf16_t* Qb = Q + (long)bh * SEQ * DHEAD;
  const bf16_t* Kb = K + (long)bh * SEQ * DHEAD;
  const bf16_t* Vb = Vt + (long)bh * DHEAD * SEQ;

  // B-operand: Q rows (q = q0+c), k-halves [0,32)+[32,64)
  const u16x8 bq0 = *(const u16x8*)(Qb + (q0 + c) * DHEAD + g * 8);
  const u16x8 bq1 = *(const u16x8*)(Qb + (q0 + c) * DHEAD + 32 + g * 8);

  float m = -1e30f, l = 0.f;
  f32x4 oacc[4];
#pragma unroll
  for (int d = 0; d < 4; ++d) oacc[d] = (f32x4){0.f, 0.f, 0.f, 0.f};

  const int srcL = c + 16 * ((2 * g) & 3);      // shfl source, words 0-1
  const int srcH = c + 16 * ((2 * g + 1) & 3);  // words 2-3
  const bool glo = (g < 2);

  for (int t0 = 0; t0 < SEQ; t0 += 32) {
    f32x4 s0 = (f32x4){0.f, 0.f, 0.f, 0.f};
    f32x4 s1 = s0;
    u16x8 ak;
    ak = *(const u16x8*)(Kb + (t0 + c) * DHEAD + g * 8);            s0 = mfma16(ak, bq0, s0);
    ak = *(const u16x8*)(Kb + (t0 + c) * DHEAD + 32 + g * 8);       s0 = mfma16(ak, bq1, s0);
    ak = *(const u16x8*)(Kb + (t0 + 16 + c) * DHEAD + g * 8);       s1 = mfma16(ak, bq0, s1);
    ak = *(const u16x8*)(Kb + (t0 + 16 + c) * DHEAD + 32 + g * 8);  s1 = mfma16(ak, bq1, s1);
    // s0[r] = S[t0+4g+r][q0+c], s1[r] = S[t0+16+4g+r][q0+c]  (log2 units)

    float pm = fmaxf(fmaxf(fmaxf(s0[0], s0[1]), fmaxf(s0[2], s0[3])),
                     fmaxf(fmaxf(s1[0], s1[1]), fmaxf(s1[2], s1[3])));
    pm = fmaxf(pm, __shfl_xor(pm, 16));
    pm = fmaxf(pm, __shfl_xor(pm, 32));
    const float mn = fmaxf(m, pm);
    const float f = EXP2F(m - mn);
    m = mn;
    float p[8];
#pragma unroll
    for (int r = 0; r < 4; ++r) p[r] = EXP2F(s0[r] - mn);
#pragma unroll
    for (int r = 0; r < 4; ++r) p[4 + r] = EXP2F(s1[r] - mn);
    float ts = ((p[0] + p[1]) + (p[2] + p[3])) + ((p[4] + p[5]) + (p[6] + p[7]));
    ts += __shfl_xor(ts, 16);
    ts += __shfl_xor(ts, 32);
    l = l * f + ts;

    // pack p -> 4 words of 2xbf16; redistribute into PV A-frag order
    const int w0 = (int)pack_bf16(p[0], p[1]);  // t=4g+0,1 (this lane's q col)
    const int w1 = (int)pack_bf16(p[2], p[3]);
    const int w2 = (int)pack_bf16(p[4], p[5]);  // t=16+4g+0,1
    const int w3 = (int)pack_bf16(p[6], p[7]);
    const int a0L = __shfl(w0, srcL), a2L = __shfl(w2, srcL);
    const int a1L = __shfl(w1, srcL), a3L = __shfl(w3, srcL);
    const int a0H = __shfl(w0, srcH), a2H = __shfl(w2, srcH);
    const int a1H = __shfl(w1, srcH), a3H = __shfl(w3, srcH);
    union { int u[4]; u16x8 v; } pu;
    pu.u[0] = glo ? a0L : a2L;  // tau = 8g+0,1
    pu.u[1] = glo ? a1L : a3L;  // tau = 8g+2,3
    pu.u[2] = glo ? a0H : a2H;  // tau = 8g+4,5
    pu.u[3] = glo ? a1H : a3H;  // tau = 8g+6,7

    // rescale O: factor belongs to row q=4g+r, held by lane 4g+r
    float fb[4];
#pragma unroll
    for (int r = 0; r < 4; ++r) fb[r] = __shfl(f, 4 * g + r);
#pragma unroll
    for (int d = 0; d < 4; ++d)
#pragma unroll
      for (int r = 0; r < 4; ++r) oacc[d][r] *= fb[r];

#pragma unroll
    for (int d = 0; d < 4; ++d) {
      const u16x8 bv = *(const u16x8*)(Vb + (long)(d * 16 + c) * SEQ + t0 + g * 8);
      oacc[d] = mfma16(pu.v, bv, oacc[d]);
    }
  }

  const int b = bh >> 4, h = bh & 15;
#pragma unroll
  for (int r = 0; r < 4; ++r) {
    const float inv = 1.f / __shfl(l, 4 * g + r);
    const long base = ((long)b * SEQ + q0 + g * 4 + r) * D_MODEL + h * DHEAD;
#pragma unroll
    for (int d = 0; d < 4; ++d) O[base + d * 16 + c] = f2bf(oacc[d][r] * inv);
  }
}

// ============================================================================
// Fused residual + LayerNorm: out = LN(X + Y)*gamma + beta.
// X: fp32 input (XF32=1) or internal bf16. Y: internal bf16.
// OUTF32=1 -> fp32 store (final output), else bf16.
// ============================================================================
template <int XF32, int OUTF32>
__global__ __launch_bounds__(256) void add_ln(
    const void* __restrict__ X, const bf16_t* __restrict__ Y,
    const float* __restrict__ gamma, const float* __restrict__ beta,
    void* __restrict__ Out) {
  __shared__ float red[2][4];
  const int tid = threadIdx.x;
  const int lane = tid & 63, w = tid >> 6;
  const long base = (long)blockIdx.x * D_MODEL;

  float xv[4];
  if (XF32) {
    const float4 t = *(const float4*)((const float*)X + base + tid * 4);
    xv[0] = t.x; xv[1] = t.y; xv[2] = t.z; xv[3] = t.w;
  } else {
    const u16x4 t = *(const u16x4*)((const bf16_t*)X + base + tid * 4);
#pragma unroll
    for (int i = 0; i < 4; ++i) xv[i] = bf2f(t[i]);
  }
  const u16x4 yv = *(const u16x4*)(Y + base + tid * 4);
  float v[4], s = 0.f, s2 = 0.f;
#pragma unroll
  for (int i = 0; i < 4; ++i) {
    const float t = xv[i] + bf2f(yv[i]);
    v[i] = t;
    s += t;
    s2 += t * t;
  }
#pragma unroll
  for (int off = 32; off; off >>= 1) {
    s += __shfl_xor(s, off);
    s2 += __shfl_xor(s2, off);
  }
  if (lane == 0) { red[0][w] = s; red[1][w] = s2; }
  __syncthreads();
  s = red[0][0] + red[0][1] + red[0][2] + red[0][3];
  s2 = red[1][0] + red[1][1] + red[1][2] + red[1][3];
  const float mu = s * (1.f / D_MODEL);
  const float var = s2 * (1.f / D_MODEL) - mu * mu;
  const float inv = rsqrtf(var + 1e-5f);
  const float4 gv = *(const float4*)(gamma + tid * 4);
  const float4 bv = *(const float4*)(beta + tid * 4);
  const float o0 = (v[0] - mu) * inv * gv.x + bv.x;
  const float o1 = (v[1] - mu) * inv * gv.y + bv.y;
  const float o2 = (v[2] - mu) * inv * gv.z + bv.z;
  const float o3 = (v[3] - mu) * inv * gv.w + bv.w;
  if (OUTF32) {
    float4 ov; ov.x = o0; ov.y = o1; ov.z = o2; ov.w = o3;
    *(float4*)((float*)Out + base + tid * 4) = ov;
  } else {
    u16x4 ov;
    ov[0] = f2bf(o0); ov[1] = f2bf(o1); ov[2] = f2bf(o2); ov[3] = f2bf(o3);
    *(u16x4*)((bf16_t*)Out + base + tid * 4) = ov;
  }
}

// ============================================================================
extern "C" void kernel_launch(void* const* d_in, const int* in_sizes, int n_in,
                              void* d_out, int out_size, void* d_ws, size_t ws_size,
                              hipStream_t stream) {
  const float* src = (const float*)d_in[0];
  const float* qw = (const float*)d_in[1];
  const float* qb = (const float*)d_in[2];
  const float* kw = (const float*)d_in[3];
  const float* kb = (const float*)d_in[4];
  const float* vw = (const float*)d_in[5];
  const float* vb = (const float*)d_in[6];
  const float* ow = (const float*)d_in[7];
  const float* ob = (const float*)d_in[8];
  const float* w1 = (const float*)d_in[9];
  const float* b1 = (const float*)d_in[10];
  const float* w2 = (const float*)d_in[11];
  const float* b2 = (const float*)d_in[12];
  const float* gam1 = (const float*)d_in[13];
  const float* bet1 = (const float*)d_in[14];
  const float* gam2 = (const float*)d_in[15];
  const float* bet2 = (const float*)d_in[16];

  char* ws = (char*)d_ws;
  const long MB = 1024 * 1024;
  bf16_t* Qw = (bf16_t*)(ws + 0 * MB);    // [B,H,S,DH]  8MB
  bf16_t* Kw = (bf16_t*)(ws + 8 * MB);    // [B,H,S,DH]  8MB
  bf16_t* Vt = (bf16_t*)(ws + 16 * MB);   // [B,H,DH,S]  8MB
  bf16_t* A1 = (bf16_t*)(ws + 24 * MB);   // attn out [M,1024] 8MB
  bf16_t* T1 = (bf16_t*)(ws + 32 * MB);   // o-proj / ff2 out  8MB
  bf16_t* X1 = (bf16_t*)(ws + 40 * MB);   // post-LN1          8MB
  bf16_t* srcB = (bf16_t*)(ws + 48 * MB); // bf16 src          8MB
  bf16_t* F1 = (bf16_t*)(ws + 0 * MB);    // ff1 [M,4096] 32MB (reuses Q/K/V/A1)

  const int M = BATCH * SEQ;  // 4096
  dim3 blk(256);
  dim3 grid_n1024(1024 / 128, M / 128);
  dim3 grid_n4096(4096 / 128, M / 128);
  const long nsrc = (long)M * D_MODEL;
  const float qscale = 0.125f * LOG2E;  // folded softmax scale, exp2 domain

  cvt_f32_bf16<<<dim3(nsrc / (256 * 8)), blk, 0, stream>>>(src, srcB, nsrc);
  gemm_bt<1, 0><<<grid_n1024, blk, 0, stream>>>(srcB, qw, qb, Qw, M, 1024, 1024, 0, qscale);
  gemm_bt<1, 0><<<grid_n1024, blk, 0, stream>>>(srcB, kw, kb, Kw, M, 1024, 1024, 0, 1.f);
  gemm_bt<2, 0><<<grid_n1024, blk, 0, stream>>>(srcB, vw, vb, Vt, M, 1024, 1024, 0, 1.f);
  attn_fwd<<<dim3(SEQ / 64, BATCH * NHEAD), blk, 0, stream>>>(Qw, Kw, Vt, A1);
  gemm_bt<0, 0><<<grid_n1024, blk, 0, stream>>>(A1, ow, ob, T1, M, 1024, 1024, 0, 1.f);
  add_ln<1, 0><<<dim3(M), blk, 0, stream>>>(src, T1, gam1, bet1, X1);
  gemm_bt<0, 0><<<grid_n4096, blk, 0, stream>>>(X1, w1, b1, F1, M, 4096, 1024, 1, 1.f);
  gemm_bt<0, 0><<<grid_n1024, blk, 0, stream>>>(F1, w2, b2, T1, M, 1024, 4096, 0, 1.f);
  add_ln<0, 1><<<dim3(M), blk, 0, stream>>>(X1, T1, gam2, bet2, d_out);
}

// Round 6
// 463.886 us; speedup vs baseline: 1.2495x; 1.2196x over previous
//
#include <hip/hip_runtime.h>

// ---- raw bf16 bits as unsigned short ----
typedef unsigned short bf16_t;
typedef unsigned short u16x8 __attribute__((ext_vector_type(8)));
typedef unsigned short u16x4 __attribute__((ext_vector_type(4)));
typedef float f32x4 __attribute__((ext_vector_type(4)));

#define D_MODEL 1024
#define NHEAD 16
#define DHEAD 64
#define FF_DIM 4096
#define SEQ 2048
#define BATCH 2
#define LOG2E 1.44269504088896340736f
#define EXP2F(x) __builtin_amdgcn_exp2f(x)

#define GLOAD_LDS16(gp, lp)                                          \
  __builtin_amdgcn_global_load_lds(                                  \
      (const __attribute__((address_space(1))) void*)(gp),           \
      (__attribute__((address_space(3))) void*)(lp), 16, 0, 0)

static __device__ __forceinline__ float bf2f(bf16_t b) {
  union { unsigned u; float f; } x;
  x.u = ((unsigned)b) << 16;
  return x.f;
}
static __device__ __forceinline__ bf16_t f2bf(float f) {
  union { float f; unsigned u; } x;
  x.f = f;
  unsigned r = (x.u + 0x7fffu + ((x.u >> 16) & 1u)) >> 16;
  return (bf16_t)r;
}
static __device__ __forceinline__ int pack_bf16(float lo, float hi) {
  return (int)((unsigned)f2bf(lo) | ((unsigned)f2bf(hi) << 16));
}
static __device__ __forceinline__ f32x4 mfma16(u16x8 a, u16x8 b, f32x4 c) {
  return __builtin_amdgcn_mfma_f32_16x16x32_bf16(a, b, c, 0, 0, 0);
}
static __device__ __forceinline__ u16x8 load8_f32(const float* q) {
  const float4 v0 = *(const float4*)(q);
  const float4 v1 = *(const float4*)(q + 4);
  u16x8 r;
  r[0] = f2bf(v0.x); r[1] = f2bf(v0.y); r[2] = f2bf(v0.z); r[3] = f2bf(v0.w);
  r[4] = f2bf(v1.x); r[5] = f2bf(v1.y); r[6] = f2bf(v1.z); r[7] = f2bf(v1.w);
  return r;
}

// ============================================================================
// fp32 -> bf16 bulk convert (n multiple of 2048)
// ============================================================================
__global__ __launch_bounds__(256) void cvt_f32_bf16(
    const float* __restrict__ in, bf16_t* __restrict__ out, long n) {
  const long i = ((long)blockIdx.x * 256 + threadIdx.x) * 8;
  if (i < n) *(u16x8*)(out + i) = load8_f32(in + i);
}

// ============================================================================
// m97-structure GEMM: C = act(A[M,K] @ W[N,K]^T + bias) ; all operands bf16,
// bias fp32. BM x 128 tile, BK=32, global_load_lds width-16, linear LDS.
// SMODE 0: C0[M,N].  SMODE 3 (fused QKV, N=3072): seg 0 -> C0 Q-layout
// [B,H,S,DH] scaled by qscale; seg 1 -> C1 K-layout; seg 2 -> C2 V^T layout.
// ============================================================================
template <int BM, int SMODE>
__global__ __launch_bounds__(256) void gemm_lds(
    const bf16_t* __restrict__ A, const bf16_t* __restrict__ W,
    const float* __restrict__ bq_, const float* __restrict__ bk_,
    const float* __restrict__ bv_, bf16_t* __restrict__ C0,
    bf16_t* __restrict__ C1, bf16_t* __restrict__ C2,
    int M, int N, int K, int relu, float qscale) {
  constexpr int WM = BM / 2;   // wave tile rows
  constexpr int MI = WM / 16;  // acc row-frags
  __shared__ bf16_t As[BM * 32];
  __shared__ bf16_t Bs[128 * 32];
  const int tid = threadIdx.x;
  const int lane = tid & 63;
  const int w = tid >> 6;
  const int wr = w >> 1, wc = w & 1;
  const int g = lane >> 4, c = lane & 15;
  const long bm = (long)blockIdx.y * BM;
  const long bn = (long)blockIdx.x * 128;

  f32x4 acc[MI][4];
#pragma unroll
  for (int i = 0; i < MI; ++i)
#pragma unroll
    for (int j = 0; j < 4; ++j) acc[i][j] = (f32x4){0.f, 0.f, 0.f, 0.f};

  for (int k0 = 0; k0 < K; k0 += 32) {
    __syncthreads();  // previous iteration's ds_reads complete
#pragma unroll
    for (int ld = 0; ld < BM / 64; ++ld) {
      const int ch = ld * 256 + tid;  // chunk: row=ch>>2, col8=(ch&3)*8
      GLOAD_LDS16(A + (bm + (ch >> 2)) * (long)K + k0 + (ch & 3) * 8,
                  As + (ld * 256 + w * 64) * 8);
    }
#pragma unroll
    for (int ld = 0; ld < 2; ++ld) {
      const int ch = ld * 256 + tid;
      GLOAD_LDS16(W + (bn + (ch >> 2)) * (long)K + k0 + (ch & 3) * 8,
                  Bs + (ld * 256 + w * 64) * 8);
    }
    __syncthreads();  // loads landed (compiler drains vmcnt before barrier)
    u16x8 af[MI], bfv[4];
#pragma unroll
    for (int i = 0; i < MI; ++i)
      af[i] = *(const u16x8*)(As + (wr * WM + i * 16 + c) * 32 + g * 8);
#pragma unroll
    for (int j = 0; j < 4; ++j)
      bfv[j] = *(const u16x8*)(Bs + (wc * 64 + j * 16 + c) * 32 + g * 8);
    __builtin_amdgcn_s_setprio(1);
#pragma unroll
    for (int i = 0; i < MI; ++i)
#pragma unroll
      for (int j = 0; j < 4; ++j) acc[i][j] = mfma16(af[i], bfv[j], acc[i][j]);
    __builtin_amdgcn_s_setprio(0);
  }

  // epilogue: D frag row=(lane>>4)*4+r, col=lane&15
#pragma unroll
  for (int i = 0; i < MI; ++i) {
#pragma unroll
    for (int j = 0; j < 4; ++j) {
      const int nn = (int)bn + wc * 64 + j * 16 + c;
#pragma unroll
      for (int r = 0; r < 4; ++r) {
        const int mm = (int)bm + wr * WM + i * 16 + g * 4 + r;
        if (SMODE == 0) {
          float v = acc[i][j][r] + bq_[nn];
          if (relu) v = fmaxf(v, 0.f);
          C0[(long)mm * N + nn] = f2bf(v);
        } else {
          const int seg = nn >> 10;  // uniform per block (128-wide tile)
          const int col = nn & 1023;
          const int h = col >> 6, dh = col & 63;
          const int b = mm >> 11, s = mm & 2047;
          if (seg == 0) {
            const float v = (acc[i][j][r] + bq_[col]) * qscale;
            C0[((((long)b * NHEAD + h) * SEQ + s) << 6) + dh] = f2bf(v);
          } else if (seg == 1) {
            const float v = acc[i][j][r] + bk_[col];
            C1[((((long)b * NHEAD + h) * SEQ + s) << 6) + dh] = f2bf(v);
          } else {
            const float v = acc[i][j][r] + bv_[col];
            C2[(((long)b * NHEAD + h) * DHEAD + dh) * SEQ + s] = f2bf(v);
          }
        }
      }
    }
  }
}

// ============================================================================
// Flash attention, swapped-QK in-register softmax, KVBLK=64, defer-max,
// deferred l-reduction. Q pre-scaled by 0.125*log2e (exp2 domain).
// Q,K [B*H,S,64]; Vt [B*H,64,S]; bf16. No LDS, no barriers.
// Per wave: 16 q rows (q=q0+c). Lane (g,c) holds S[t in 4g+r+{0,16,32,48}][q=c].
// ============================================================================
__global__ __launch_bounds__(256, 4) void attn_fwd(
    const bf16_t* __restrict__ Q, const bf16_t* __restrict__ K,
    const bf16_t* __restrict__ Vt, bf16_t* __restrict__ O) {
  const int tid = threadIdx.x;
  const int lane = tid & 63;
  const int w = tid >> 6;
  const int g = lane >> 4, c = lane & 15;
  const int bh = blockIdx.y;
  const int q0 = blockIdx.x * 64 + w * 16;
  const bf16_t* Qb = Q + (long)bh * SEQ * DHEAD;
  const bf16_t* Kb = K + (long)bh * SEQ * DHEAD;
  const bf16_t* Vb = Vt + (long)bh * DHEAD * SEQ;

  const u16x8 bq0 = *(const u16x8*)(Qb + (q0 + c) * DHEAD + g * 8);
  const u16x8 bq1 = *(const u16x8*)(Qb + (q0 + c) * DHEAD + 32 + g * 8);

  float m = -1e30f, lp = 0.f;  // m per q=c (uniform over g); lp per-lane partial
  f32x4 oacc[4];
#pragma unroll
  for (int d = 0; d < 4; ++d) oacc[d] = (f32x4){0.f, 0.f, 0.f, 0.f};

  const int srcA = c + 16 * (2 * (g & 1));  // source lane, k-lo half
  const int srcH = srcA + 16;               // k-hi half
  const bool glo2 = (g < 2);

  for (int t0 = 0; t0 < SEQ; t0 += 64) {
    // ---- K tile into regs (dies after QK) ----
    u16x8 kf[8];
#pragma unroll
    for (int tt = 0; tt < 4; ++tt) {
      kf[tt * 2 + 0] = *(const u16x8*)(Kb + (t0 + tt * 16 + c) * DHEAD + g * 8);
      kf[tt * 2 + 1] = *(const u16x8*)(Kb + (t0 + tt * 16 + c) * DHEAD + 32 + g * 8);
    }
    f32x4 s[4];
    __builtin_amdgcn_s_setprio(1);
#pragma unroll
    for (int tt = 0; tt < 4; ++tt) {
      s[tt] = mfma16(kf[tt * 2 + 0], bq0, (f32x4){0.f, 0.f, 0.f, 0.f});
      s[tt] = mfma16(kf[tt * 2 + 1], bq1, s[tt]);
    }
    __builtin_amdgcn_s_setprio(0);
    // ---- V tile into regs; latency covered by softmax ----
    u16x8 vf[8];
#pragma unroll
    for (int d = 0; d < 4; ++d) {
      vf[d * 2 + 0] = *(const u16x8*)(Vb + (long)(d * 16 + c) * SEQ + t0 + g * 8);
      vf[d * 2 + 1] = *(const u16x8*)(Vb + (long)(d * 16 + c) * SEQ + t0 + 32 + g * 8);
    }

    // ---- softmax (exp2 domain) ----
    float pm = s[0][0];
#pragma unroll
    for (int tt = 0; tt < 4; ++tt)
#pragma unroll
      for (int r = 0; r < 4; ++r) pm = fmaxf(pm, s[tt][r]);
    pm = fmaxf(pm, __shfl_xor(pm, 16));
    pm = fmaxf(pm, __shfl_xor(pm, 32));
    if (!__all(pm <= m + 8.f)) {  // defer-max: rescale only on real growth
      const float mn = fmaxf(m, pm);
      const float f = EXP2F(m - mn);
      m = mn;
      lp *= f;
      float fb[4];
#pragma unroll
      for (int r = 0; r < 4; ++r) fb[r] = __shfl(f, 4 * g + r);
#pragma unroll
      for (int d = 0; d < 4; ++d)
#pragma unroll
        for (int r = 0; r < 4; ++r) oacc[d][r] *= fb[r];
    }
    float p[16];
#pragma unroll
    for (int tt = 0; tt < 4; ++tt)
#pragma unroll
      for (int r = 0; r < 4; ++r) p[tt * 4 + r] = EXP2F(s[tt][r] - m);
    float ts = 0.f;
#pragma unroll
    for (int i = 0; i < 16; ++i) ts += p[i];
    lp += ts;  // cross-g reduce deferred to epilogue

    // ---- pack + redistribute into PV A-frags ----
    int wd[8];
#pragma unroll
    for (int tt = 0; tt < 4; ++tt) {
      wd[tt * 2 + 0] = pack_bf16(p[tt * 4 + 0], p[tt * 4 + 1]);
      wd[tt * 2 + 1] = pack_bf16(p[tt * 4 + 2], p[tt * 4 + 3]);
    }
    union { int u[4]; u16x8 v; } pu0, pu1;
    pu0.u[0] = glo2 ? __shfl(wd[0], srcA) : __shfl(wd[2], srcA);
    pu0.u[1] = glo2 ? __shfl(wd[1], srcA) : __shfl(wd[3], srcA);
    pu0.u[2] = glo2 ? __shfl(wd[0], srcH) : __shfl(wd[2], srcH);
    pu0.u[3] = glo2 ? __shfl(wd[1], srcH) : __shfl(wd[3], srcH);
    pu1.u[0] = glo2 ? __shfl(wd[4], srcA) : __shfl(wd[6], srcA);
    pu1.u[1] = glo2 ? __shfl(wd[5], srcA) : __shfl(wd[7], srcA);
    pu1.u[2] = glo2 ? __shfl(wd[4], srcH) : __shfl(wd[6], srcH);
    pu1.u[3] = glo2 ? __shfl(wd[5], srcH) : __shfl(wd[7], srcH);

    // ---- PV ----
    __builtin_amdgcn_s_setprio(1);
#pragma unroll
    for (int d = 0; d < 4; ++d) {
      oacc[d] = mfma16(pu0.v, vf[d * 2 + 0], oacc[d]);
      oacc[d] = mfma16(pu1.v, vf[d * 2 + 1], oacc[d]);
    }
    __builtin_amdgcn_s_setprio(0);
  }

  float lt = lp;
  lt += __shfl_xor(lt, 16);
  lt += __shfl_xor(lt, 32);
  const int b = bh >> 4, h = bh & 15;
#pragma unroll
  for (int r = 0; r < 4; ++r) {
    const float inv = 1.f / __shfl(lt, 4 * g + r);
    const long base = ((long)b * SEQ + q0 + g * 4 + r) * D_MODEL + h * DHEAD;
#pragma unroll
    for (int d = 0; d < 4; ++d) O[base + d * 16 + c] = f2bf(oacc[d][r] * inv);
  }
}

// ============================================================================
// Fused residual + LayerNorm: out = LN(X + Y)*gamma + beta.
// ============================================================================
template <int XF32, int OUTF32>
__global__ __launch_bounds__(256) void add_ln(
    const void* __restrict__ X, const bf16_t* __restrict__ Y,
    const float* __restrict__ gamma, const float* __restrict__ beta,
    void* __restrict__ Out) {
  __shared__ float red[2][4];
  const int tid = threadIdx.x;
  const int lane = tid & 63, w = tid >> 6;
  const long base = (long)blockIdx.x * D_MODEL;

  float xv[4];
  if (XF32) {
    const float4 t = *(const float4*)((const float*)X + base + tid * 4);
    xv[0] = t.x; xv[1] = t.y; xv[2] = t.z; xv[3] = t.w;
  } else {
    const u16x4 t = *(const u16x4*)((const bf16_t*)X + base + tid * 4);
#pragma unroll
    for (int i = 0; i < 4; ++i) xv[i] = bf2f(t[i]);
  }
  const u16x4 yv = *(const u16x4*)(Y + base + tid * 4);
  float v[4], s = 0.f, s2 = 0.f;
#pragma unroll
  for (int i = 0; i < 4; ++i) {
    const float t = xv[i] + bf2f(yv[i]);
    v[i] = t;
    s += t;
    s2 += t * t;
  }
#pragma unroll
  for (int off = 32; off; off >>= 1) {
    s += __shfl_xor(s, off);
    s2 += __shfl_xor(s2, off);
  }
  if (lane == 0) { red[0][w] = s; red[1][w] = s2; }
  __syncthreads();
  s = red[0][0] + red[0][1] + red[0][2] + red[0][3];
  s2 = red[1][0] + red[1][1] + red[1][2] + red[1][3];
  const float mu = s * (1.f / D_MODEL);
  const float var = s2 * (1.f / D_MODEL) - mu * mu;
  const float inv = rsqrtf(var + 1e-5f);
  const float4 gv = *(const float4*)(gamma + tid * 4);
  const float4 bv = *(const float4*)(beta + tid * 4);
  const float o0 = (v[0] - mu) * inv * gv.x + bv.x;
  const float o1 = (v[1] - mu) * inv * gv.y + bv.y;
  const float o2 = (v[2] - mu) * inv * gv.z + bv.z;
  const float o3 = (v[3] - mu) * inv * gv.w + bv.w;
  if (OUTF32) {
    float4 ov; ov.x = o0; ov.y = o1; ov.z = o2; ov.w = o3;
    *(float4*)((float*)Out + base + tid * 4) = ov;
  } else {
    u16x4 ov;
    ov[0] = f2bf(o0); ov[1] = f2bf(o1); ov[2] = f2bf(o2); ov[3] = f2bf(o3);
    *(u16x4*)((bf16_t*)Out + base + tid * 4) = ov;
  }
}

// ============================================================================
extern "C" void kernel_launch(void* const* d_in, const int* in_sizes, int n_in,
                              void* d_out, int out_size, void* d_ws, size_t ws_size,
                              hipStream_t stream) {
  const float* src = (const float*)d_in[0];
  const float* qw = (const float*)d_in[1];
  const float* qb = (const float*)d_in[2];
  const float* kw = (const float*)d_in[3];
  const float* kb = (const float*)d_in[4];
  const float* vw = (const float*)d_in[5];
  const float* vb = (const float*)d_in[6];
  const float* ow = (const float*)d_in[7];
  const float* ob = (const float*)d_in[8];
  const float* w1 = (const float*)d_in[9];
  const float* b1 = (const float*)d_in[10];
  const float* w2 = (const float*)d_in[11];
  const float* b2 = (const float*)d_in[12];
  const float* gam1 = (const float*)d_in[13];
  const float* bet1 = (const float*)d_in[14];
  const float* gam2 = (const float*)d_in[15];
  const float* bet2 = (const float*)d_in[16];

  char* ws = (char*)d_ws;
  const long MB = 1024 * 1024;
  bf16_t* Qw   = (bf16_t*)(ws + 0 * MB);   // [B,H,S,DH] 8MB
  bf16_t* Kw   = (bf16_t*)(ws + 8 * MB);   // 8MB
  bf16_t* Vt   = (bf16_t*)(ws + 16 * MB);  // [B,H,DH,S] 8MB
  bf16_t* A1   = (bf16_t*)(ws + 24 * MB);  // attn out 8MB
  bf16_t* T1   = (bf16_t*)(ws + 32 * MB);  // o-proj / ff2 out 8MB
  bf16_t* X1   = (bf16_t*)(ws + 40 * MB);  // post-LN1 8MB
  bf16_t* srcB = (bf16_t*)(ws + 48 * MB);  // bf16 src 8MB
  bf16_t* Wqkv = (bf16_t*)(ws + 56 * MB);  // [3072,1024] bf16 6MB
  bf16_t* OWb  = (bf16_t*)(ws + 62 * MB);  // [1024,1024] 2MB
  bf16_t* W1b  = (bf16_t*)(ws + 64 * MB);  // [4096,1024] 8MB
  bf16_t* W2b  = (bf16_t*)(ws + 72 * MB);  // [1024,4096] 8MB
  bf16_t* F1   = (bf16_t*)(ws + 0 * MB);   // ff1 [M,4096] 32MB (overlays Q/K/V/A1)

  const int M = BATCH * SEQ;  // 4096
  dim3 blk(256);
  const float qscale = 0.125f * LOG2E;
  const long n1M = 1024 * 1024;

  // weight / input conversion (fp32 -> bf16), QKV weights concatenated
  cvt_f32_bf16<<<dim3(2048), blk, 0, stream>>>(src, srcB, (long)M * D_MODEL);
  cvt_f32_bf16<<<dim3(512), blk, 0, stream>>>(qw, Wqkv, n1M);
  cvt_f32_bf16<<<dim3(512), blk, 0, stream>>>(kw, Wqkv + n1M, n1M);
  cvt_f32_bf16<<<dim3(512), blk, 0, stream>>>(vw, Wqkv + 2 * n1M, n1M);
  cvt_f32_bf16<<<dim3(512), blk, 0, stream>>>(ow, OWb, n1M);
  cvt_f32_bf16<<<dim3(2048), blk, 0, stream>>>(w1, W1b, 4 * n1M);
  cvt_f32_bf16<<<dim3(2048), blk, 0, stream>>>(w2, W2b, 4 * n1M);

  // fused QKV projection: M=4096, N=3072, K=1024
  gemm_lds<128, 3><<<dim3(24, 32), blk, 0, stream>>>(
      srcB, Wqkv, qb, kb, vb, Qw, Kw, Vt, M, 3072, 1024, 0, qscale);
  attn_fwd<<<dim3(SEQ / 64, BATCH * NHEAD), blk, 0, stream>>>(Qw, Kw, Vt, A1);
  gemm_lds<64, 0><<<dim3(8, 64), blk, 0, stream>>>(
      A1, OWb, ob, ob, ob, T1, T1, T1, M, 1024, 1024, 0, 1.f);
  add_ln<1, 0><<<dim3(M), blk, 0, stream>>>(src, T1, gam1, bet1, X1);
  gemm_lds<128, 0><<<dim3(32, 32), blk, 0, stream>>>(
      X1, W1b, b1, b1, b1, F1, F1, F1, M, 4096, 1024, 1, 1.f);
  gemm_lds<64, 0><<<dim3(8, 64), blk, 0, stream>>>(
      F1, W2b, b2, b2, b2, T1, T1, T1, M, 1024, 4096, 0, 1.f);
  add_ln<0, 1><<<dim3(M), blk, 0, stream>>>(X1, T1, gam2, bet2, d_out);
}

// Round 7
// 309.826 us; speedup vs baseline: 1.8707x; 1.4972x over previous
//
#include <hip/hip_runtime.h>

// ---- raw bf16 bits as unsigned short ----
typedef unsigned short bf16_t;
typedef unsigned short u16x8 __attribute__((ext_vector_type(8)));
typedef unsigned short u16x4 __attribute__((ext_vector_type(4)));
typedef float f32x4 __attribute__((ext_vector_type(4)));

#define D_MODEL 1024
#define NHEAD 16
#define DHEAD 64
#define FF_DIM 4096
#define SEQ 2048
#define BATCH 2
#define LOG2E 1.44269504088896340736f
#define EXP2F(x) __builtin_amdgcn_exp2f(x)

#define GLOAD_LDS16(gp, lp)                                          \
  __builtin_amdgcn_global_load_lds(                                  \
      (const __attribute__((address_space(1))) void*)(gp),           \
      (__attribute__((address_space(3))) void*)(lp), 16, 0, 0)

static __device__ __forceinline__ float bf2f(bf16_t b) {
  union { unsigned u; float f; } x;
  x.u = ((unsigned)b) << 16;
  return x.f;
}
static __device__ __forceinline__ bf16_t f2bf(float f) {
  union { float f; unsigned u; } x;
  x.f = f;
  unsigned r = (x.u + 0x7fffu + ((x.u >> 16) & 1u)) >> 16;
  return (bf16_t)r;
}
static __device__ __forceinline__ int pack_bf16(float lo, float hi) {
  return (int)((unsigned)f2bf(lo) | ((unsigned)f2bf(hi) << 16));
}
static __device__ __forceinline__ f32x4 mfma16(u16x8 a, u16x8 b, f32x4 c) {
  return __builtin_amdgcn_mfma_f32_16x16x32_bf16(a, b, c, 0, 0, 0);
}
static __device__ __forceinline__ u16x8 load8_f32(const float* q) {
  const float4 v0 = *(const float4*)(q);
  const float4 v1 = *(const float4*)(q + 4);
  u16x8 r;
  r[0] = f2bf(v0.x); r[1] = f2bf(v0.y); r[2] = f2bf(v0.z); r[3] = f2bf(v0.w);
  r[4] = f2bf(v1.x); r[5] = f2bf(v1.y); r[6] = f2bf(v1.z); r[7] = f2bf(v1.w);
  return r;
}

// ============================================================================
// fp32 -> bf16 bulk convert (n multiple of 2048)
// ============================================================================
__global__ __launch_bounds__(256) void cvt_f32_bf16(
    const float* __restrict__ in, bf16_t* __restrict__ out, long n) {
  const long i = ((long)blockIdx.x * 256 + threadIdx.x) * 8;
  if (i < n) *(u16x8*)(out + i) = load8_f32(in + i);
}

// ============================================================================
// m97-structure GEMM: C = act(A[M,K] @ W[N,K]^T + bias) ; operands bf16,
// bias fp32. BM x 128 tile, BK=32, global_load_lds width-16, linear LDS.
// SMODE 0: C0[M,N].  SMODE 3 (fused QKV, N=3072): seg 0 -> Q [B,H,S,DH]
// * qscale; seg 1 -> K layout; seg 2 -> V^T layout.
// ============================================================================
template <int BM, int SMODE>
__global__ __launch_bounds__(256) void gemm_lds(
    const bf16_t* __restrict__ A, const bf16_t* __restrict__ W,
    const float* __restrict__ bq_, const float* __restrict__ bk_,
    const float* __restrict__ bv_, bf16_t* __restrict__ C0,
    bf16_t* __restrict__ C1, bf16_t* __restrict__ C2,
    int M, int N, int K, int relu, float qscale) {
  constexpr int WM = BM / 2;   // wave tile rows
  constexpr int MI = WM / 16;  // acc row-frags
  __shared__ bf16_t As[BM * 32];
  __shared__ bf16_t Bs[128 * 32];
  const int tid = threadIdx.x;
  const int lane = tid & 63;
  const int w = tid >> 6;
  const int wr = w >> 1, wc = w & 1;
  const int g = lane >> 4, c = lane & 15;
  const long bm = (long)blockIdx.y * BM;
  const long bn = (long)blockIdx.x * 128;

  f32x4 acc[MI][4];
#pragma unroll
  for (int i = 0; i < MI; ++i)
#pragma unroll
    for (int j = 0; j < 4; ++j) acc[i][j] = (f32x4){0.f, 0.f, 0.f, 0.f};

  for (int k0 = 0; k0 < K; k0 += 32) {
    __syncthreads();  // previous iteration's ds_reads complete
#pragma unroll
    for (int ld = 0; ld < BM / 64; ++ld) {
      const int ch = ld * 256 + tid;  // chunk: row=ch>>2, col8=(ch&3)*8
      GLOAD_LDS16(A + (bm + (ch >> 2)) * (long)K + k0 + (ch & 3) * 8,
                  As + (ld * 256 + w * 64) * 8);
    }
#pragma unroll
    for (int ld = 0; ld < 2; ++ld) {
      const int ch = ld * 256 + tid;
      GLOAD_LDS16(W + (bn + (ch >> 2)) * (long)K + k0 + (ch & 3) * 8,
                  Bs + (ld * 256 + w * 64) * 8);
    }
    __syncthreads();  // loads landed
    u16x8 af[MI], bfv[4];
#pragma unroll
    for (int i = 0; i < MI; ++i)
      af[i] = *(const u16x8*)(As + (wr * WM + i * 16 + c) * 32 + g * 8);
#pragma unroll
    for (int j = 0; j < 4; ++j)
      bfv[j] = *(const u16x8*)(Bs + (wc * 64 + j * 16 + c) * 32 + g * 8);
    __builtin_amdgcn_s_setprio(1);
#pragma unroll
    for (int i = 0; i < MI; ++i)
#pragma unroll
      for (int j = 0; j < 4; ++j) acc[i][j] = mfma16(af[i], bfv[j], acc[i][j]);
    __builtin_amdgcn_s_setprio(0);
  }

  // epilogue: D frag row=(lane>>4)*4+r, col=lane&15
#pragma unroll
  for (int i = 0; i < MI; ++i) {
#pragma unroll
    for (int j = 0; j < 4; ++j) {
      const int nn = (int)bn + wc * 64 + j * 16 + c;
#pragma unroll
      for (int r = 0; r < 4; ++r) {
        const int mm = (int)bm + wr * WM + i * 16 + g * 4 + r;
        if (SMODE == 0) {
          float v = acc[i][j][r] + bq_[nn];
          if (relu) v = fmaxf(v, 0.f);
          C0[(long)mm * N + nn] = f2bf(v);
        } else {
          const int seg = nn >> 10;  // uniform per block (128-wide tile)
          const int col = nn & 1023;
          const int h = col >> 6, dh = col & 63;
          const int b = mm >> 11, s = mm & 2047;
          if (seg == 0) {
            const float v = (acc[i][j][r] + bq_[col]) * qscale;
            C0[((((long)b * NHEAD + h) * SEQ + s) << 6) + dh] = f2bf(v);
          } else if (seg == 1) {
            const float v = acc[i][j][r] + bk_[col];
            C1[((((long)b * NHEAD + h) * SEQ + s) << 6) + dh] = f2bf(v);
          } else {
            const float v = acc[i][j][r] + bv_[col];
            C2[(((long)b * NHEAD + h) * DHEAD + dh) * SEQ + s] = f2bf(v);
          }
        }
      }
    }
  }
}

// ============================================================================
// stage a 64x64 bf16 tile (global row-major, row stride rstride elems) into
// LDS linear [64][64] with per-row chunk XOR swizzle: LDS[row][c4] holds
// global chunk (c4 ^ (row&7)). Dest is wave-uniform base (HW adds lane*16).
// ============================================================================
static __device__ __forceinline__ void stage_tile(
    const bf16_t* __restrict__ gbase, long rstride, bf16_t* lds,
    int tid, int w) {
#pragma unroll
  for (int i = 0; i < 2; ++i) {
    const int row = i * 32 + (tid >> 3);
    const int c4 = (tid & 7) ^ (row & 7);
    GLOAD_LDS16(gbase + (long)row * rstride + c4 * 8,
                lds + (i * 256 + w * 64) * 8);
  }
}

// ============================================================================
// Flash attention: swapped-QK in-register softmax + LDS-shared K/V tiles +
// XCD-aware block swizzle (4 heads per XCD -> K/V L2-resident).
// Q pre-scaled by 0.125*log2e (exp2 domain). Q,K [B*H,S,64]; Vt [B*H,64,S].
// Per wave: 16 q rows (q=q0+c). Lane (g,c): S[t=4g+r+16tt][q=c].
// ============================================================================
__global__ __launch_bounds__(256, 4) void attn_fwd(
    const bf16_t* __restrict__ Q, const bf16_t* __restrict__ K,
    const bf16_t* __restrict__ Vt, bf16_t* __restrict__ O) {
  __shared__ bf16_t Ks[64 * 64];
  __shared__ bf16_t Vs[64 * 64];
  const int tid = threadIdx.x;
  const int lane = tid & 63;
  const int w = tid >> 6;
  const int g = lane >> 4, c = lane & 15;
  // XCD swizzle: 1024 blocks, xcd = lb&7 (round-robin heuristic);
  // each XCD gets heads [4*xcd .. 4*xcd+3] -> 2MB K/V working set.
  const int lb = blockIdx.x;
  const int xcd = lb & 7, sl = lb >> 3;
  const int bh = xcd * 4 + (sl >> 5);
  const int q0 = (sl & 31) * 64 + w * 16;
  const bf16_t* Qb = Q + (long)bh * SEQ * DHEAD;
  const bf16_t* Kb = K + (long)bh * SEQ * DHEAD;
  const bf16_t* Vb = Vt + (long)bh * DHEAD * SEQ;

  const u16x8 bq0 = *(const u16x8*)(Qb + (q0 + c) * DHEAD + g * 8);
  const u16x8 bq1 = *(const u16x8*)(Qb + (q0 + c) * DHEAD + 32 + g * 8);

  float m = -1e30f, lp = 0.f;
  f32x4 oacc[4];
#pragma unroll
  for (int d = 0; d < 4; ++d) oacc[d] = (f32x4){0.f, 0.f, 0.f, 0.f};

  const int srcA = c + 16 * (2 * (g & 1));
  const int srcH = srcA + 16;
  const bool glo2 = (g < 2);
  const int cx = c & 7;  // read-side swizzle key (row&7 == c&7 for our rows)

  for (int t0 = 0; t0 < SEQ; t0 += 64) {
    __syncthreads();  // previous iteration's ds_reads complete
    stage_tile(Kb + (long)t0 * DHEAD, DHEAD, Ks, tid, w);
    stage_tile(Vb + t0, SEQ, Vs, tid, w);
    __syncthreads();  // loads landed

    // ---- QK^T from LDS (swizzled read) ----
    u16x8 kf[8];
#pragma unroll
    for (int tt = 0; tt < 4; ++tt) {
      const int rowb = (tt * 16 + c) * 64;
      kf[tt * 2 + 0] = *(const u16x8*)(Ks + rowb + ((g ^ cx)) * 8);
      kf[tt * 2 + 1] = *(const u16x8*)(Ks + rowb + (((4 + g) ^ cx)) * 8);
    }
    f32x4 s[4];
    __builtin_amdgcn_s_setprio(1);
#pragma unroll
    for (int tt = 0; tt < 4; ++tt) {
      s[tt] = mfma16(kf[tt * 2 + 0], bq0, (f32x4){0.f, 0.f, 0.f, 0.f});
      s[tt] = mfma16(kf[tt * 2 + 1], bq1, s[tt]);
    }
    __builtin_amdgcn_s_setprio(0);

    // ---- softmax (exp2 domain), defer-max ----
    float pm = s[0][0];
#pragma unroll
    for (int tt = 0; tt < 4; ++tt)
#pragma unroll
      for (int r = 0; r < 4; ++r) pm = fmaxf(pm, s[tt][r]);
    pm = fmaxf(pm, __shfl_xor(pm, 16));
    pm = fmaxf(pm, __shfl_xor(pm, 32));
    if (!__all(pm <= m + 8.f)) {
      const float mn = fmaxf(m, pm);
      const float f = EXP2F(m - mn);
      m = mn;
      lp *= f;
      float fb[4];
#pragma unroll
      for (int r = 0; r < 4; ++r) fb[r] = __shfl(f, 4 * g + r);
#pragma unroll
      for (int d = 0; d < 4; ++d)
#pragma unroll
        for (int r = 0; r < 4; ++r) oacc[d][r] *= fb[r];
    }
    float p[16];
#pragma unroll
    for (int tt = 0; tt < 4; ++tt)
#pragma unroll
      for (int r = 0; r < 4; ++r) p[tt * 4 + r] = EXP2F(s[tt][r] - m);
    float ts = 0.f;
#pragma unroll
    for (int i = 0; i < 16; ++i) ts += p[i];
    lp += ts;

    // ---- pack + redistribute into PV A-frags ----
    int wd[8];
#pragma unroll
    for (int tt = 0; tt < 4; ++tt) {
      wd[tt * 2 + 0] = pack_bf16(p[tt * 4 + 0], p[tt * 4 + 1]);
      wd[tt * 2 + 1] = pack_bf16(p[tt * 4 + 2], p[tt * 4 + 3]);
    }
    union { int u[4]; u16x8 v; } pu0, pu1;
    pu0.u[0] = glo2 ? __shfl(wd[0], srcA) : __shfl(wd[2], srcA);
    pu0.u[1] = glo2 ? __shfl(wd[1], srcA) : __shfl(wd[3], srcA);
    pu0.u[2] = glo2 ? __shfl(wd[0], srcH) : __shfl(wd[2], srcH);
    pu0.u[3] = glo2 ? __shfl(wd[1], srcH) : __shfl(wd[3], srcH);
    pu1.u[0] = glo2 ? __shfl(wd[4], srcA) : __shfl(wd[6], srcA);
    pu1.u[1] = glo2 ? __shfl(wd[5], srcA) : __shfl(wd[7], srcA);
    pu1.u[2] = glo2 ? __shfl(wd[4], srcH) : __shfl(wd[6], srcH);
    pu1.u[3] = glo2 ? __shfl(wd[5], srcH) : __shfl(wd[7], srcH);

    // ---- PV from LDS (swizzled read) ----
    __builtin_amdgcn_s_setprio(1);
#pragma unroll
    for (int d = 0; d < 4; ++d) {
      const int rowb = (d * 16 + c) * 64;
      const u16x8 v0 = *(const u16x8*)(Vs + rowb + ((g ^ cx)) * 8);
      const u16x8 v1 = *(const u16x8*)(Vs + rowb + (((4 + g) ^ cx)) * 8);
      oacc[d] = mfma16(pu0.v, v0, oacc[d]);
      oacc[d] = mfma16(pu1.v, v1, oacc[d]);
    }
    __builtin_amdgcn_s_setprio(0);
  }

  float lt = lp;
  lt += __shfl_xor(lt, 16);
  lt += __shfl_xor(lt, 32);
  const int b = bh >> 4, h = bh & 15;
#pragma unroll
  for (int r = 0; r < 4; ++r) {
    const float inv = 1.f / __shfl(lt, 4 * g + r);
    const long base = ((long)b * SEQ + q0 + g * 4 + r) * D_MODEL + h * DHEAD;
#pragma unroll
    for (int d = 0; d < 4; ++d) O[base + d * 16 + c] = f2bf(oacc[d][r] * inv);
  }
}

// ============================================================================
// Fused residual + LayerNorm: out = LN(X + Y)*gamma + beta.
// ============================================================================
template <int XF32, int OUTF32>
__global__ __launch_bounds__(256) void add_ln(
    const void* __restrict__ X, const bf16_t* __restrict__ Y,
    const float* __restrict__ gamma, const float* __restrict__ beta,
    void* __restrict__ Out) {
  __shared__ float red[2][4];
  const int tid = threadIdx.x;
  const int lane = tid & 63, w = tid >> 6;
  const long base = (long)blockIdx.x * D_MODEL;

  float xv[4];
  if (XF32) {
    const float4 t = *(const float4*)((const float*)X + base + tid * 4);
    xv[0] = t.x; xv[1] = t.y; xv[2] = t.z; xv[3] = t.w;
  } else {
    const u16x4 t = *(const u16x4*)((const bf16_t*)X + base + tid * 4);
#pragma unroll
    for (int i = 0; i < 4; ++i) xv[i] = bf2f(t[i]);
  }
  const u16x4 yv = *(const u16x4*)(Y + base + tid * 4);
  float v[4], s = 0.f, s2 = 0.f;
#pragma unroll
  for (int i = 0; i < 4; ++i) {
    const float t = xv[i] + bf2f(yv[i]);
    v[i] = t;
    s += t;
    s2 += t * t;
  }
#pragma unroll
  for (int off = 32; off; off >>= 1) {
    s += __shfl_xor(s, off);
    s2 += __shfl_xor(s2, off);
  }
  if (lane == 0) { red[0][w] = s; red[1][w] = s2; }
  __syncthreads();
  s = red[0][0] + red[0][1] + red[0][2] + red[0][3];
  s2 = red[1][0] + red[1][1] + red[1][2] + red[1][3];
  const float mu = s * (1.f / D_MODEL);
  const float var = s2 * (1.f / D_MODEL) - mu * mu;
  const float inv = rsqrtf(var + 1e-5f);
  const float4 gv = *(const float4*)(gamma + tid * 4);
  const float4 bv = *(const float4*)(beta + tid * 4);
  const float o0 = (v[0] - mu) * inv * gv.x + bv.x;
  const float o1 = (v[1] - mu) * inv * gv.y + bv.y;
  const float o2 = (v[2] - mu) * inv * gv.z + bv.z;
  const float o3 = (v[3] - mu) * inv * gv.w + bv.w;
  if (OUTF32) {
    float4 ov; ov.x = o0; ov.y = o1; ov.z = o2; ov.w = o3;
    *(float4*)((float*)Out + base + tid * 4) = ov;
  } else {
    u16x4 ov;
    ov[0] = f2bf(o0); ov[1] = f2bf(o1); ov[2] = f2bf(o2); ov[3] = f2bf(o3);
    *(u16x4*)((bf16_t*)Out + base + tid * 4) = ov;
  }
}

// ============================================================================
extern "C" void kernel_launch(void* const* d_in, const int* in_sizes, int n_in,
                              void* d_out, int out_size, void* d_ws, size_t ws_size,
                              hipStream_t stream) {
  const float* src = (const float*)d_in[0];
  const float* qw = (const float*)d_in[1];
  const float* qb = (const float*)d_in[2];
  const float* kw = (const float*)d_in[3];
  const float* kb = (const float*)d_in[4];
  const float* vw = (const float*)d_in[5];
  const float* vb = (const float*)d_in[6];
  const float* ow = (const float*)d_in[7];
  const float* ob = (const float*)d_in[8];
  const float* w1 = (const float*)d_in[9];
  const float* b1 = (const float*)d_in[10];
  const float* w2 = (const float*)d_in[11];
  const float* b2 = (const float*)d_in[12];
  const float* gam1 = (const float*)d_in[13];
  const float* bet1 = (const float*)d_in[14];
  const float* gam2 = (const float*)d_in[15];
  const float* bet2 = (const float*)d_in[16];

  char* ws = (char*)d_ws;
  const long MB = 1024 * 1024;
  bf16_t* Qw   = (bf16_t*)(ws + 0 * MB);   // [B,H,S,DH] 8MB
  bf16_t* Kw   = (bf16_t*)(ws + 8 * MB);   // 8MB
  bf16_t* Vt   = (bf16_t*)(ws + 16 * MB);  // [B,H,DH,S] 8MB
  bf16_t* A1   = (bf16_t*)(ws + 24 * MB);  // attn out 8MB
  bf16_t* T1   = (bf16_t*)(ws + 32 * MB);  // o-proj / ff2 out 8MB
  bf16_t* X1   = (bf16_t*)(ws + 40 * MB);  // post-LN1 8MB
  bf16_t* srcB = (bf16_t*)(ws + 48 * MB);  // bf16 src 8MB
  bf16_t* Wqkv = (bf16_t*)(ws + 56 * MB);  // [3072,1024] bf16 6MB
  bf16_t* OWb  = (bf16_t*)(ws + 62 * MB);  // [1024,1024] 2MB
  bf16_t* W1b  = (bf16_t*)(ws + 64 * MB);  // [4096,1024] 8MB
  bf16_t* W2b  = (bf16_t*)(ws + 72 * MB);  // [1024,4096] 8MB
  bf16_t* F1   = (bf16_t*)(ws + 0 * MB);   // ff1 [M,4096] 32MB (overlays Q/K/V/A1)

  const int M = BATCH * SEQ;  // 4096
  dim3 blk(256);
  const float qscale = 0.125f * LOG2E;
  const long n1M = 1024 * 1024;

  cvt_f32_bf16<<<dim3(2048), blk, 0, stream>>>(src, srcB, (long)M * D_MODEL);
  cvt_f32_bf16<<<dim3(512), blk, 0, stream>>>(qw, Wqkv, n1M);
  cvt_f32_bf16<<<dim3(512), blk, 0, stream>>>(kw, Wqkv + n1M, n1M);
  cvt_f32_bf16<<<dim3(512), blk, 0, stream>>>(vw, Wqkv + 2 * n1M, n1M);
  cvt_f32_bf16<<<dim3(512), blk, 0, stream>>>(ow, OWb, n1M);
  cvt_f32_bf16<<<dim3(2048), blk, 0, stream>>>(w1, W1b, 4 * n1M);
  cvt_f32_bf16<<<dim3(2048), blk, 0, stream>>>(w2, W2b, 4 * n1M);

  gemm_lds<128, 3><<<dim3(24, 32), blk, 0, stream>>>(
      srcB, Wqkv, qb, kb, vb, Qw, Kw, Vt, M, 3072, 1024, 0, qscale);
  attn_fwd<<<dim3(1024), blk, 0, stream>>>(Qw, Kw, Vt, A1);
  gemm_lds<64, 0><<<dim3(8, 64), blk, 0, stream>>>(
      A1, OWb, ob, ob, ob, T1, T1, T1, M, 1024, 1024, 0, 1.f);
  add_ln<1, 0><<<dim3(M), blk, 0, stream>>>(src, T1, gam1, bet1, X1);
  gemm_lds<128, 0><<<dim3(32, 32), blk, 0, stream>>>(
      X1, W1b, b1, b1, b1, F1, F1, F1, M, 4096, 1024, 1, 1.f);
  gemm_lds<64, 0><<<dim3(8, 64), blk, 0, stream>>>(
      F1, W2b, b2, b2, b2, T1, T1, T1, M, 1024, 4096, 0, 1.f);
  add_ln<0, 1><<<dim3(M), blk, 0, stream>>>(X1, T1, gam2, bet2, d_out);
}

// Round 8
// 300.642 us; speedup vs baseline: 1.9279x; 1.0305x over previous
//
#include <hip/hip_runtime.h>

// ---- raw bf16 bits as unsigned short ----
typedef unsigned short bf16_t;
typedef unsigned short u16x8 __attribute__((ext_vector_type(8)));
typedef unsigned short u16x4 __attribute__((ext_vector_type(4)));
typedef float f32x4 __attribute__((ext_vector_type(4)));

#define D_MODEL 1024
#define NHEAD 16
#define DHEAD 64
#define FF_DIM 4096
#define SEQ 2048
#define BATCH 2
#define LOG2E 1.44269504088896340736f
#define EXP2F(x) __builtin_amdgcn_exp2f(x)

#define GLOAD_LDS16(gp, lp)                                          \
  __builtin_amdgcn_global_load_lds(                                  \
      (const __attribute__((address_space(1))) void*)(gp),           \
      (__attribute__((address_space(3))) void*)(lp), 16, 0, 0)

static __device__ __forceinline__ float bf2f(bf16_t b) {
  union { unsigned u; float f; } x;
  x.u = ((unsigned)b) << 16;
  return x.f;
}
static __device__ __forceinline__ bf16_t f2bf(float f) {
  union { float f; unsigned u; } x;
  x.f = f;
  unsigned r = (x.u + 0x7fffu + ((x.u >> 16) & 1u)) >> 16;
  return (bf16_t)r;
}
static __device__ __forceinline__ int pack_bf16(float lo, float hi) {
  return (int)((unsigned)f2bf(lo) | ((unsigned)f2bf(hi) << 16));
}
static __device__ __forceinline__ f32x4 mfma16(u16x8 a, u16x8 b, f32x4 c) {
  return __builtin_amdgcn_mfma_f32_16x16x32_bf16(a, b, c, 0, 0, 0);
}
static __device__ __forceinline__ u16x8 load8_f32(const float* q) {
  const float4 v0 = *(const float4*)(q);
  const float4 v1 = *(const float4*)(q + 4);
  u16x8 r;
  r[0] = f2bf(v0.x); r[1] = f2bf(v0.y); r[2] = f2bf(v0.z); r[3] = f2bf(v0.w);
  r[4] = f2bf(v1.x); r[5] = f2bf(v1.y); r[6] = f2bf(v1.z); r[7] = f2bf(v1.w);
  return r;
}

// ============================================================================
// fp32 -> bf16 bulk convert (n multiple of 2048)
// ============================================================================
__global__ __launch_bounds__(256) void cvt_f32_bf16(
    const float* __restrict__ in, bf16_t* __restrict__ out, long n) {
  const long i = ((long)blockIdx.x * 256 + threadIdx.x) * 8;
  if (i < n) *(u16x8*)(out + i) = load8_f32(in + i);
}

// ============================================================================
// m97-structure GEMM over a K-segment: operands bf16, bias fp32.
// BM x 128 tile, BK=32, global_load_lds width-16, linear LDS.
// K-loop covers Kseg elems starting at blockIdx.z*Kseg (row strides lda/ldw).
// SMODE 0: C0[M,N] = act(.+bias)        (grid.z == 1)
// SMODE 3: fused QKV (N=3072): seg0 -> Q [B,H,S,DH] * qscale; seg1 -> K;
//          seg2 -> V^T                  (grid.z == 1)
// SMODE 4: split-K fp32 partials, no bias/act: (z ? CP1 : CP0)[mm*N+nn]
// ============================================================================
template <int BM, int SMODE>
__global__ __launch_bounds__(256) void gemm_lds(
    const bf16_t* __restrict__ A, const bf16_t* __restrict__ W,
    const float* __restrict__ bq_, const float* __restrict__ bk_,
    const float* __restrict__ bv_, bf16_t* __restrict__ C0,
    bf16_t* __restrict__ C1, bf16_t* __restrict__ C2,
    float* __restrict__ CP0, float* __restrict__ CP1,
    int M, int N, int Kseg, long lda, long ldw, int relu, float qscale) {
  constexpr int WM = BM / 2;   // wave tile rows
  constexpr int MI = WM / 16;  // acc row-frags
  __shared__ bf16_t As[BM * 32];
  __shared__ bf16_t Bs[128 * 32];
  const int tid = threadIdx.x;
  const int lane = tid & 63;
  const int w = tid >> 6;
  const int wr = w >> 1, wc = w & 1;
  const int g = lane >> 4, c = lane & 15;
  const long bm = (long)blockIdx.y * BM;
  const long bn = (long)blockIdx.x * 128;
  const long koff = (long)blockIdx.z * Kseg;

  f32x4 acc[MI][4];
#pragma unroll
  for (int i = 0; i < MI; ++i)
#pragma unroll
    for (int j = 0; j < 4; ++j) acc[i][j] = (f32x4){0.f, 0.f, 0.f, 0.f};

  for (int k0 = 0; k0 < Kseg; k0 += 32) {
    __syncthreads();  // previous iteration's ds_reads complete
#pragma unroll
    for (int ld = 0; ld < BM / 64; ++ld) {
      const int ch = ld * 256 + tid;  // chunk: row=ch>>2, col8=(ch&3)*8
      GLOAD_LDS16(A + (bm + (ch >> 2)) * lda + koff + k0 + (ch & 3) * 8,
                  As + (ld * 256 + w * 64) * 8);
    }
#pragma unroll
    for (int ld = 0; ld < 2; ++ld) {
      const int ch = ld * 256 + tid;
      GLOAD_LDS16(W + (bn + (ch >> 2)) * ldw + koff + k0 + (ch & 3) * 8,
                  Bs + (ld * 256 + w * 64) * 8);
    }
    __syncthreads();  // loads landed
    u16x8 af[MI], bfv[4];
#pragma unroll
    for (int i = 0; i < MI; ++i)
      af[i] = *(const u16x8*)(As + (wr * WM + i * 16 + c) * 32 + g * 8);
#pragma unroll
    for (int j = 0; j < 4; ++j)
      bfv[j] = *(const u16x8*)(Bs + (wc * 64 + j * 16 + c) * 32 + g * 8);
    __builtin_amdgcn_s_setprio(1);
#pragma unroll
    for (int i = 0; i < MI; ++i)
#pragma unroll
      for (int j = 0; j < 4; ++j) acc[i][j] = mfma16(af[i], bfv[j], acc[i][j]);
    __builtin_amdgcn_s_setprio(0);
  }

  float* __restrict__ cp = blockIdx.z ? CP1 : CP0;
  // epilogue: D frag row=(lane>>4)*4+r, col=lane&15
#pragma unroll
  for (int i = 0; i < MI; ++i) {
#pragma unroll
    for (int j = 0; j < 4; ++j) {
      const int nn = (int)bn + wc * 64 + j * 16 + c;
#pragma unroll
      for (int r = 0; r < 4; ++r) {
        const int mm = (int)bm + wr * WM + i * 16 + g * 4 + r;
        if (SMODE == 0) {
          float v = acc[i][j][r] + bq_[nn];
          if (relu) v = fmaxf(v, 0.f);
          C0[(long)mm * N + nn] = f2bf(v);
        } else if (SMODE == 4) {
          cp[(long)mm * N + nn] = acc[i][j][r];
        } else {
          const int seg = nn >> 10;  // uniform per block (128-wide tile)
          const int col = nn & 1023;
          const int h = col >> 6, dh = col & 63;
          const int b = mm >> 11, s = mm & 2047;
          if (seg == 0) {
            const float v = (acc[i][j][r] + bq_[col]) * qscale;
            C0[((((long)b * NHEAD + h) * SEQ + s) << 6) + dh] = f2bf(v);
          } else if (seg == 1) {
            const float v = acc[i][j][r] + bk_[col];
            C1[((((long)b * NHEAD + h) * SEQ + s) << 6) + dh] = f2bf(v);
          } else {
            const float v = acc[i][j][r] + bv_[col];
            C2[(((long)b * NHEAD + h) * DHEAD + dh) * SEQ + s] = f2bf(v);
          }
        }
      }
    }
  }
}

// ============================================================================
// stage a 64x64 bf16 tile (global row-major, row stride rstride elems) into
// LDS linear [64][64] with per-row chunk XOR swizzle.
// ============================================================================
static __device__ __forceinline__ void stage_tile(
    const bf16_t* __restrict__ gbase, long rstride, bf16_t* lds,
    int tid, int w) {
#pragma unroll
  for (int i = 0; i < 2; ++i) {
    const int row = i * 32 + (tid >> 3);
    const int c4 = (tid & 7) ^ (row & 7);
    GLOAD_LDS16(gbase + (long)row * rstride + c4 * 8,
                lds + (i * 256 + w * 64) * 8);
  }
}

// ============================================================================
// Flash attention: swapped-QK in-register softmax + LDS-shared K/V tiles +
// XCD-aware block swizzle. Q pre-scaled by 0.125*log2e (exp2 domain).
// ============================================================================
__global__ __launch_bounds__(256, 4) void attn_fwd(
    const bf16_t* __restrict__ Q, const bf16_t* __restrict__ K,
    const bf16_t* __restrict__ Vt, bf16_t* __restrict__ O) {
  __shared__ bf16_t Ks[64 * 64];
  __shared__ bf16_t Vs[64 * 64];
  const int tid = threadIdx.x;
  const int lane = tid & 63;
  const int w = tid >> 6;
  const int g = lane >> 4, c = lane & 15;
  const int lb = blockIdx.x;
  const int xcd = lb & 7, sl = lb >> 3;
  const int bh = xcd * 4 + (sl >> 5);
  const int q0 = (sl & 31) * 64 + w * 16;
  const bf16_t* Qb = Q + (long)bh * SEQ * DHEAD;
  const bf16_t* Kb = K + (long)bh * SEQ * DHEAD;
  const bf16_t* Vb = Vt + (long)bh * DHEAD * SEQ;

  const u16x8 bq0 = *(const u16x8*)(Qb + (q0 + c) * DHEAD + g * 8);
  const u16x8 bq1 = *(const u16x8*)(Qb + (q0 + c) * DHEAD + 32 + g * 8);

  float m = -1e30f, lp = 0.f;
  f32x4 oacc[4];
#pragma unroll
  for (int d = 0; d < 4; ++d) oacc[d] = (f32x4){0.f, 0.f, 0.f, 0.f};

  const int srcA = c + 16 * (2 * (g & 1));
  const int srcH = srcA + 16;
  const bool glo2 = (g < 2);
  const int cx = c & 7;

  for (int t0 = 0; t0 < SEQ; t0 += 64) {
    __syncthreads();
    stage_tile(Kb + (long)t0 * DHEAD, DHEAD, Ks, tid, w);
    stage_tile(Vb + t0, SEQ, Vs, tid, w);
    __syncthreads();

    // ---- QK^T from LDS (swizzled read) ----
    u16x8 kf[8];
#pragma unroll
    for (int tt = 0; tt < 4; ++tt) {
      const int rowb = (tt * 16 + c) * 64;
      kf[tt * 2 + 0] = *(const u16x8*)(Ks + rowb + ((g ^ cx)) * 8);
      kf[tt * 2 + 1] = *(const u16x8*)(Ks + rowb + (((4 + g) ^ cx)) * 8);
    }
    f32x4 s[4];
    __builtin_amdgcn_s_setprio(1);
#pragma unroll
    for (int tt = 0; tt < 4; ++tt) {
      s[tt] = mfma16(kf[tt * 2 + 0], bq0, (f32x4){0.f, 0.f, 0.f, 0.f});
      s[tt] = mfma16(kf[tt * 2 + 1], bq1, s[tt]);
    }
    __builtin_amdgcn_s_setprio(0);

    // ---- softmax (exp2 domain), defer-max ----
    float pm = s[0][0];
#pragma unroll
    for (int tt = 0; tt < 4; ++tt)
#pragma unroll
      for (int r = 0; r < 4; ++r) pm = fmaxf(pm, s[tt][r]);
    pm = fmaxf(pm, __shfl_xor(pm, 16));
    pm = fmaxf(pm, __shfl_xor(pm, 32));
    if (!__all(pm <= m + 8.f)) {
      const float mn = fmaxf(m, pm);
      const float f = EXP2F(m - mn);
      m = mn;
      lp *= f;
      float fb[4];
#pragma unroll
      for (int r = 0; r < 4; ++r) fb[r] = __shfl(f, 4 * g + r);
#pragma unroll
      for (int d = 0; d < 4; ++d)
#pragma unroll
        for (int r = 0; r < 4; ++r) oacc[d][r] *= fb[r];
    }
    float p[16];
#pragma unroll
    for (int tt = 0; tt < 4; ++tt)
#pragma unroll
      for (int r = 0; r < 4; ++r) p[tt * 4 + r] = EXP2F(s[tt][r] - m);
    float ts = 0.f;
#pragma unroll
    for (int i = 0; i < 16; ++i) ts += p[i];
    lp += ts;

    // ---- pack + redistribute into PV A-frags ----
    int wd[8];
#pragma unroll
    for (int tt = 0; tt < 4; ++tt) {
      wd[tt * 2 + 0] = pack_bf16(p[tt * 4 + 0], p[tt * 4 + 1]);
      wd[tt * 2 + 1] = pack_bf16(p[tt * 4 + 2], p[tt * 4 + 3]);
    }
    union { int u[4]; u16x8 v; } pu0, pu1;
    pu0.u[0] = glo2 ? __shfl(wd[0], srcA) : __shfl(wd[2], srcA);
    pu0.u[1] = glo2 ? __shfl(wd[1], srcA) : __shfl(wd[3], srcA);
    pu0.u[2] = glo2 ? __shfl(wd[0], srcH) : __shfl(wd[2], srcH);
    pu0.u[3] = glo2 ? __shfl(wd[1], srcH) : __shfl(wd[3], srcH);
    pu1.u[0] = glo2 ? __shfl(wd[4], srcA) : __shfl(wd[6], srcA);
    pu1.u[1] = glo2 ? __shfl(wd[5], srcA) : __shfl(wd[7], srcA);
    pu1.u[2] = glo2 ? __shfl(wd[4], srcH) : __shfl(wd[6], srcH);
    pu1.u[3] = glo2 ? __shfl(wd[5], srcH) : __shfl(wd[7], srcH);

    // ---- PV from LDS (swizzled read) ----
    __builtin_amdgcn_s_setprio(1);
#pragma unroll
    for (int d = 0; d < 4; ++d) {
      const int rowb = (d * 16 + c) * 64;
      const u16x8 v0 = *(const u16x8*)(Vs + rowb + ((g ^ cx)) * 8);
      const u16x8 v1 = *(const u16x8*)(Vs + rowb + (((4 + g) ^ cx)) * 8);
      oacc[d] = mfma16(pu0.v, v0, oacc[d]);
      oacc[d] = mfma16(pu1.v, v1, oacc[d]);
    }
    __builtin_amdgcn_s_setprio(0);
  }

  float lt = lp;
  lt += __shfl_xor(lt, 16);
  lt += __shfl_xor(lt, 32);
  const int b = bh >> 4, h = bh & 15;
#pragma unroll
  for (int r = 0; r < 4; ++r) {
    const float inv = 1.f / __shfl(lt, 4 * g + r);
    const long base = ((long)b * SEQ + q0 + g * 4 + r) * D_MODEL + h * DHEAD;
#pragma unroll
    for (int d = 0; d < 4; ++d) O[base + d * 16 + c] = f2bf(oacc[d][r] * inv);
  }
}

// ============================================================================
// Fused residual + LayerNorm: out = LN(X + Y)*gamma + beta.
// YPART=0: Y = bf16 buffer. YPART=1: Y = P0 + P1 + ybias (fp32 split-K
// partials; deterministic fixed-order reduce).
// ============================================================================
template <int XF32, int OUTF32, int YPART>
__global__ __launch_bounds__(256) void add_ln(
    const void* __restrict__ X, const bf16_t* __restrict__ Ybf,
    const float* __restrict__ P0, const float* __restrict__ P1,
    const float* __restrict__ ybias,
    const float* __restrict__ gamma, const float* __restrict__ beta,
    void* __restrict__ Out) {
  __shared__ float red[2][4];
  const int tid = threadIdx.x;
  const int lane = tid & 63, w = tid >> 6;
  const long base = (long)blockIdx.x * D_MODEL;

  float xv[4];
  if (XF32) {
    const float4 t = *(const float4*)((const float*)X + base + tid * 4);
    xv[0] = t.x; xv[1] = t.y; xv[2] = t.z; xv[3] = t.w;
  } else {
    const u16x4 t = *(const u16x4*)((const bf16_t*)X + base + tid * 4);
#pragma unroll
    for (int i = 0; i < 4; ++i) xv[i] = bf2f(t[i]);
  }
  float yv[4];
  if (YPART) {
    const float4 p0 = *(const float4*)(P0 + base + tid * 4);
    const float4 p1 = *(const float4*)(P1 + base + tid * 4);
    const float4 bb = *(const float4*)(ybias + tid * 4);
    yv[0] = p0.x + p1.x + bb.x;
    yv[1] = p0.y + p1.y + bb.y;
    yv[2] = p0.z + p1.z + bb.z;
    yv[3] = p0.w + p1.w + bb.w;
  } else {
    const u16x4 t = *(const u16x4*)(Ybf + base + tid * 4);
#pragma unroll
    for (int i = 0; i < 4; ++i) yv[i] = bf2f(t[i]);
  }
  float v[4], s = 0.f, s2 = 0.f;
#pragma unroll
  for (int i = 0; i < 4; ++i) {
    const float t = xv[i] + yv[i];
    v[i] = t;
    s += t;
    s2 += t * t;
  }
#pragma unroll
  for (int off = 32; off; off >>= 1) {
    s += __shfl_xor(s, off);
    s2 += __shfl_xor(s2, off);
  }
  if (lane == 0) { red[0][w] = s; red[1][w] = s2; }
  __syncthreads();
  s = red[0][0] + red[0][1] + red[0][2] + red[0][3];
  s2 = red[1][0] + red[1][1] + red[1][2] + red[1][3];
  const float mu = s * (1.f / D_MODEL);
  const float var = s2 * (1.f / D_MODEL) - mu * mu;
  const float inv = rsqrtf(var + 1e-5f);
  const float4 gv = *(const float4*)(gamma + tid * 4);
  const float4 bv = *(const float4*)(beta + tid * 4);
  const float o0 = (v[0] - mu) * inv * gv.x + bv.x;
  const float o1 = (v[1] - mu) * inv * gv.y + bv.y;
  const float o2 = (v[2] - mu) * inv * gv.z + bv.z;
  const float o3 = (v[3] - mu) * inv * gv.w + bv.w;
  if (OUTF32) {
    float4 ov; ov.x = o0; ov.y = o1; ov.z = o2; ov.w = o3;
    *(float4*)((float*)Out + base + tid * 4) = ov;
  } else {
    u16x4 ov;
    ov[0] = f2bf(o0); ov[1] = f2bf(o1); ov[2] = f2bf(o2); ov[3] = f2bf(o3);
    *(u16x4*)((bf16_t*)Out + base + tid * 4) = ov;
  }
}

// ============================================================================
extern "C" void kernel_launch(void* const* d_in, const int* in_sizes, int n_in,
                              void* d_out, int out_size, void* d_ws, size_t ws_size,
                              hipStream_t stream) {
  const float* src = (const float*)d_in[0];
  const float* qw = (const float*)d_in[1];
  const float* qb = (const float*)d_in[2];
  const float* kw = (const float*)d_in[3];
  const float* kb = (const float*)d_in[4];
  const float* vw = (const float*)d_in[5];
  const float* vb = (const float*)d_in[6];
  const float* ow = (const float*)d_in[7];
  const float* ob = (const float*)d_in[8];
  const float* w1 = (const float*)d_in[9];
  const float* b1 = (const float*)d_in[10];
  const float* w2 = (const float*)d_in[11];
  const float* b2 = (const float*)d_in[12];
  const float* gam1 = (const float*)d_in[13];
  const float* bet1 = (const float*)d_in[14];
  const float* gam2 = (const float*)d_in[15];
  const float* bet2 = (const float*)d_in[16];

  char* ws = (char*)d_ws;
  const long MB = 1024 * 1024;
  // timeline-overlaid regions (peak 96MB):
  bf16_t* Qw   = (bf16_t*)(ws + 0 * MB);   // [B,H,S,DH] 8MB   (dead after attn)
  bf16_t* Kw   = (bf16_t*)(ws + 8 * MB);   // 8MB              (dead after attn)
  bf16_t* Vt   = (bf16_t*)(ws + 16 * MB);  // [B,H,DH,S] 8MB   (dead after attn)
  bf16_t* A1   = (bf16_t*)(ws + 24 * MB);  // attn out 8MB     (dead after o-proj)
  float*  Po0  = (float*)(ws + 0 * MB);    // o-proj partial0 16MB (over Qw/Kw)
  float*  Po1  = (float*)(ws + 80 * MB);   // o-proj partial1 16MB
  bf16_t* X1   = (bf16_t*)(ws + 40 * MB);  // post-LN1 8MB
  bf16_t* srcB = (bf16_t*)(ws + 48 * MB);  // bf16 src 8MB     (dead after QKV)
  bf16_t* Wqkv = (bf16_t*)(ws + 56 * MB);  // [3072,1024] 6MB  (dead after QKV)
  bf16_t* OWb  = (bf16_t*)(ws + 62 * MB);  // [1024,1024] 2MB  (dead after o-proj)
  bf16_t* W1b  = (bf16_t*)(ws + 64 * MB);  // [4096,1024] 8MB  (dead after FF1)
  bf16_t* W2b  = (bf16_t*)(ws + 72 * MB);  // [1024,4096] 8MB
  bf16_t* F1   = (bf16_t*)(ws + 0 * MB);   // ff1 [M,4096] 32MB (over Po0/Qw..A1)
  float*  P0   = (float*)(ws + 48 * MB);   // ff2 partial0 16MB (over srcB/Wqkv/OWb)
  float*  P1   = (float*)(ws + 80 * MB);   // ff2 partial1 16MB (over Po1)

  const int M = BATCH * SEQ;  // 4096
  dim3 blk(256);
  const float qscale = 0.125f * LOG2E;
  const long n1M = 1024 * 1024;

  cvt_f32_bf16<<<dim3(2048), blk, 0, stream>>>(src, srcB, (long)M * D_MODEL);
  cvt_f32_bf16<<<dim3(512), blk, 0, stream>>>(qw, Wqkv, n1M);
  cvt_f32_bf16<<<dim3(512), blk, 0, stream>>>(kw, Wqkv + n1M, n1M);
  cvt_f32_bf16<<<dim3(512), blk, 0, stream>>>(vw, Wqkv + 2 * n1M, n1M);
  cvt_f32_bf16<<<dim3(512), blk, 0, stream>>>(ow, OWb, n1M);
  cvt_f32_bf16<<<dim3(2048), blk, 0, stream>>>(w1, W1b, 4 * n1M);
  cvt_f32_bf16<<<dim3(2048), blk, 0, stream>>>(w2, W2b, 4 * n1M);

  // QKV: M=4096, N=3072, K=1024 (768 blocks)
  gemm_lds<128, 3><<<dim3(24, 32, 1), blk, 0, stream>>>(
      srcB, Wqkv, qb, kb, vb, Qw, Kw, Vt, (float*)0, (float*)0,
      M, 3072, 1024, 1024, 1024, 0, qscale);
  attn_fwd<<<dim3(1024), blk, 0, stream>>>(Qw, Kw, Vt, A1);
  // o-proj: split-K2 fp32 partials (512 blocks)
  gemm_lds<128, 4><<<dim3(8, 32, 2), blk, 0, stream>>>(
      A1, OWb, ob, ob, ob, (bf16_t*)0, (bf16_t*)0, (bf16_t*)0, Po0, Po1,
      M, 1024, 512, 1024, 1024, 0, 1.f);
  add_ln<1, 0, 1><<<dim3(M), blk, 0, stream>>>(
      src, (const bf16_t*)0, Po0, Po1, ob, gam1, bet1, X1);
  // FF1: M=4096, N=4096, K=1024 (1024 blocks)
  gemm_lds<128, 0><<<dim3(32, 32, 1), blk, 0, stream>>>(
      X1, W1b, b1, b1, b1, F1, F1, F1, (float*)0, (float*)0,
      M, 4096, 1024, 1024, 1024, 1, 1.f);
  // FF2: split-K2 fp32 partials (512 blocks)
  gemm_lds<128, 4><<<dim3(8, 32, 2), blk, 0, stream>>>(
      F1, W2b, b2, b2, b2, (bf16_t*)0, (bf16_t*)0, (bf16_t*)0, P0, P1,
      M, 1024, 2048, 4096, 4096, 0, 1.f);
  add_ln<0, 1, 1><<<dim3(M), blk, 0, stream>>>(
      X1, (const bf16_t*)0, P0, P1, b2, gam2, bet2, d_out);
}

// Round 9
// 296.726 us; speedup vs baseline: 1.9533x; 1.0132x over previous
//
#include <hip/hip_runtime.h>

// ---- raw bf16 bits as unsigned short ----
typedef unsigned short bf16_t;
typedef unsigned short u16x8 __attribute__((ext_vector_type(8)));
typedef unsigned short u16x4 __attribute__((ext_vector_type(4)));
typedef float f32x4 __attribute__((ext_vector_type(4)));

#define D_MODEL 1024
#define NHEAD 16
#define DHEAD 64
#define FF_DIM 4096
#define SEQ 2048
#define BATCH 2
#define LOG2E 1.44269504088896340736f
#define EXP2F(x) __builtin_amdgcn_exp2f(x)

#define GLOAD_LDS16(gp, lp)                                          \
  __builtin_amdgcn_global_load_lds(                                  \
      (const __attribute__((address_space(1))) void*)(gp),           \
      (__attribute__((address_space(3))) void*)(lp), 16, 0, 0)

static __device__ __forceinline__ float bf2f(bf16_t b) {
  union { unsigned u; float f; } x;
  x.u = ((unsigned)b) << 16;
  return x.f;
}
static __device__ __forceinline__ bf16_t f2bf(float f) {
  union { float f; unsigned u; } x;
  x.f = f;
  unsigned r = (x.u + 0x7fffu + ((x.u >> 16) & 1u)) >> 16;
  return (bf16_t)r;
}
// HW packed f32->bf16 (RNE), 1 instruction for 2 values [T12 recipe]
static __device__ __forceinline__ int cvtpk(float lo, float hi) {
  int r;
  asm("v_cvt_pk_bf16_f32 %0, %1, %2" : "=v"(r) : "v"(lo), "v"(hi));
  return r;
}
static __device__ __forceinline__ f32x4 mfma16(u16x8 a, u16x8 b, f32x4 c) {
  return __builtin_amdgcn_mfma_f32_16x16x32_bf16(a, b, c, 0, 0, 0);
}
static __device__ __forceinline__ u16x8 load8_f32(const float* q) {
  const float4 v0 = *(const float4*)(q);
  const float4 v1 = *(const float4*)(q + 4);
  u16x8 r;
  r[0] = f2bf(v0.x); r[1] = f2bf(v0.y); r[2] = f2bf(v0.z); r[3] = f2bf(v0.w);
  r[4] = f2bf(v1.x); r[5] = f2bf(v1.y); r[6] = f2bf(v1.z); r[7] = f2bf(v1.w);
  return r;
}

// ============================================================================
// fp32 -> bf16 bulk convert (n multiple of 2048)
// ============================================================================
__global__ __launch_bounds__(256) void cvt_f32_bf16(
    const float* __restrict__ in, bf16_t* __restrict__ out, long n) {
  const long i = ((long)blockIdx.x * 256 + threadIdx.x) * 8;
  if (i < n) *(u16x8*)(out + i) = load8_f32(in + i);
}

// ============================================================================
// m97-structure GEMM over a K-segment: operands bf16, bias fp32.
// BM x 128 tile, BK=32, global_load_lds width-16, linear LDS.
// SMODE 0: C0[M,N] = act(.+bias)        (grid.z == 1)
// SMODE 3: fused QKV (N=3072): seg0 -> Q * qscale; seg1 -> K; seg2 -> V^T
// SMODE 4: split-K fp32 partials: (z ? CP1 : CP0)[mm*N+nn]
// ============================================================================
template <int BM, int SMODE>
__global__ __launch_bounds__(256) void gemm_lds(
    const bf16_t* __restrict__ A, const bf16_t* __restrict__ W,
    const float* __restrict__ bq_, const float* __restrict__ bk_,
    const float* __restrict__ bv_, bf16_t* __restrict__ C0,
    bf16_t* __restrict__ C1, bf16_t* __restrict__ C2,
    float* __restrict__ CP0, float* __restrict__ CP1,
    int M, int N, int Kseg, long lda, long ldw, int relu, float qscale) {
  constexpr int WM = BM / 2;   // wave tile rows
  constexpr int MI = WM / 16;  // acc row-frags
  __shared__ bf16_t As[BM * 32];
  __shared__ bf16_t Bs[128 * 32];
  const int tid = threadIdx.x;
  const int lane = tid & 63;
  const int w = tid >> 6;
  const int wr = w >> 1, wc = w & 1;
  const int g = lane >> 4, c = lane & 15;
  const long bm = (long)blockIdx.y * BM;
  const long bn = (long)blockIdx.x * 128;
  const long koff = (long)blockIdx.z * Kseg;

  f32x4 acc[MI][4];
#pragma unroll
  for (int i = 0; i < MI; ++i)
#pragma unroll
    for (int j = 0; j < 4; ++j) acc[i][j] = (f32x4){0.f, 0.f, 0.f, 0.f};

  for (int k0 = 0; k0 < Kseg; k0 += 32) {
    __syncthreads();
#pragma unroll
    for (int ld = 0; ld < BM / 64; ++ld) {
      const int ch = ld * 256 + tid;
      GLOAD_LDS16(A + (bm + (ch >> 2)) * lda + koff + k0 + (ch & 3) * 8,
                  As + (ld * 256 + w * 64) * 8);
    }
#pragma unroll
    for (int ld = 0; ld < 2; ++ld) {
      const int ch = ld * 256 + tid;
      GLOAD_LDS16(W + (bn + (ch >> 2)) * ldw + koff + k0 + (ch & 3) * 8,
                  Bs + (ld * 256 + w * 64) * 8);
    }
    __syncthreads();
    u16x8 af[MI], bfv[4];
#pragma unroll
    for (int i = 0; i < MI; ++i)
      af[i] = *(const u16x8*)(As + (wr * WM + i * 16 + c) * 32 + g * 8);
#pragma unroll
    for (int j = 0; j < 4; ++j)
      bfv[j] = *(const u16x8*)(Bs + (wc * 64 + j * 16 + c) * 32 + g * 8);
    __builtin_amdgcn_s_setprio(1);
#pragma unroll
    for (int i = 0; i < MI; ++i)
#pragma unroll
      for (int j = 0; j < 4; ++j) acc[i][j] = mfma16(af[i], bfv[j], acc[i][j]);
    __builtin_amdgcn_s_setprio(0);
  }

  float* __restrict__ cp = blockIdx.z ? CP1 : CP0;
#pragma unroll
  for (int i = 0; i < MI; ++i) {
#pragma unroll
    for (int j = 0; j < 4; ++j) {
      const int nn = (int)bn + wc * 64 + j * 16 + c;
#pragma unroll
      for (int r = 0; r < 4; ++r) {
        const int mm = (int)bm + wr * WM + i * 16 + g * 4 + r;
        if (SMODE == 0) {
          float v = acc[i][j][r] + bq_[nn];
          if (relu) v = fmaxf(v, 0.f);
          C0[(long)mm * N + nn] = f2bf(v);
        } else if (SMODE == 4) {
          cp[(long)mm * N + nn] = acc[i][j][r];
        } else {
          const int seg = nn >> 10;
          const int col = nn & 1023;
          const int h = col >> 6, dh = col & 63;
          const int b = mm >> 11, s = mm & 2047;
          if (seg == 0) {
            const float v = (acc[i][j][r] + bq_[col]) * qscale;
            C0[((((long)b * NHEAD + h) * SEQ + s) << 6) + dh] = f2bf(v);
          } else if (seg == 1) {
            const float v = acc[i][j][r] + bk_[col];
            C1[((((long)b * NHEAD + h) * SEQ + s) << 6) + dh] = f2bf(v);
          } else {
            const float v = acc[i][j][r] + bv_[col];
            C2[(((long)b * NHEAD + h) * DHEAD + dh) * SEQ + s] = f2bf(v);
          }
        }
      }
    }
  }
}

// ============================================================================
// stage a 64x64 bf16 tile (row stride rstride) into LDS linear [64][64] with
// per-row chunk XOR swizzle: LDS[row][c4] holds global chunk (c4 ^ (row&7)).
// ============================================================================
static __device__ __forceinline__ void stage_tile(
    const bf16_t* __restrict__ gbase, long rstride, bf16_t* lds,
    int tid, int w) {
#pragma unroll
  for (int i = 0; i < 2; ++i) {
    const int row = i * 32 + (tid >> 3);
    const int c4 = (tid & 7) ^ (row & 7);
    GLOAD_LDS16(gbase + (long)row * rstride + c4 * 8,
                lds + (i * 256 + w * 64) * 8);
  }
}

// ============================================================================
// Flash attention: swapped-QK in-register softmax, KVBLK=128 (4x 64x64 LDS
// tiles per stage, 2 barriers per 128 kv), cvt_pk packing, defer-max,
// XCD-aware block swizzle. Q pre-scaled by 0.125*log2e (exp2 domain).
// ============================================================================
__global__ __launch_bounds__(256, 4) void attn_fwd(
    const bf16_t* __restrict__ Q, const bf16_t* __restrict__ K,
    const bf16_t* __restrict__ Vt, bf16_t* __restrict__ O) {
  __shared__ bf16_t Ks0[64 * 64];
  __shared__ bf16_t Ks1[64 * 64];
  __shared__ bf16_t Vs0[64 * 64];
  __shared__ bf16_t Vs1[64 * 64];
  const int tid = threadIdx.x;
  const int lane = tid & 63;
  const int w = tid >> 6;
  const int g = lane >> 4, c = lane & 15;
  const int lb = blockIdx.x;
  const int xcd = lb & 7, sl = lb >> 3;
  const int bh = xcd * 4 + (sl >> 5);
  const int q0 = (sl & 31) * 64 + w * 16;
  const bf16_t* Qb = Q + (long)bh * SEQ * DHEAD;
  const bf16_t* Kb = K + (long)bh * SEQ * DHEAD;
  const bf16_t* Vb = Vt + (long)bh * DHEAD * SEQ;

  const u16x8 bq0 = *(const u16x8*)(Qb + (q0 + c) * DHEAD + g * 8);
  const u16x8 bq1 = *(const u16x8*)(Qb + (q0 + c) * DHEAD + 32 + g * 8);

  float m = -1e30f, lp = 0.f;
  f32x4 oacc[4];
#pragma unroll
  for (int d = 0; d < 4; ++d) oacc[d] = (f32x4){0.f, 0.f, 0.f, 0.f};

  const int srcA = c + 16 * (2 * (g & 1));
  const int srcH = srcA + 16;
  const bool glo2 = (g < 2);
  const int cx = c & 7;

  for (int t0 = 0; t0 < SEQ; t0 += 128) {
    __syncthreads();  // all waves done reading previous tiles
    stage_tile(Kb + (long)t0 * DHEAD, DHEAD, Ks0, tid, w);
    stage_tile(Kb + (long)(t0 + 64) * DHEAD, DHEAD, Ks1, tid, w);
    stage_tile(Vb + t0, SEQ, Vs0, tid, w);
    stage_tile(Vb + t0 + 64, SEQ, Vs1, tid, w);
    __syncthreads();  // loads landed

#pragma unroll
    for (int sub = 0; sub < 2; ++sub) {
      const bf16_t* Ks = sub ? Ks1 : Ks0;
      const bf16_t* Vs = sub ? Vs1 : Vs0;

      // ---- QK^T from LDS (swizzled read) ----
      u16x8 kf[8];
#pragma unroll
      for (int tt = 0; tt < 4; ++tt) {
        const int rowb = (tt * 16 + c) * 64;
        kf[tt * 2 + 0] = *(const u16x8*)(Ks + rowb + ((g ^ cx)) * 8);
        kf[tt * 2 + 1] = *(const u16x8*)(Ks + rowb + (((4 + g) ^ cx)) * 8);
      }
      f32x4 s[4];
      __builtin_amdgcn_s_setprio(1);
#pragma unroll
      for (int tt = 0; tt < 4; ++tt) {
        s[tt] = mfma16(kf[tt * 2 + 0], bq0, (f32x4){0.f, 0.f, 0.f, 0.f});
        s[tt] = mfma16(kf[tt * 2 + 1], bq1, s[tt]);
      }
      __builtin_amdgcn_s_setprio(0);

      // ---- softmax (exp2 domain), defer-max ----
      float pm = s[0][0];
#pragma unroll
      for (int tt = 0; tt < 4; ++tt)
#pragma unroll
        for (int r = 0; r < 4; ++r) pm = fmaxf(pm, s[tt][r]);
      pm = fmaxf(pm, __shfl_xor(pm, 16));
      pm = fmaxf(pm, __shfl_xor(pm, 32));
      if (!__all(pm <= m + 8.f)) {
        const float mn = fmaxf(m, pm);
        const float f = EXP2F(m - mn);
        m = mn;
        lp *= f;
        float fb[4];
#pragma unroll
        for (int r = 0; r < 4; ++r) fb[r] = __shfl(f, 4 * g + r);
#pragma unroll
        for (int d = 0; d < 4; ++d)
#pragma unroll
          for (int r = 0; r < 4; ++r) oacc[d][r] *= fb[r];
      }
      float p[16];
#pragma unroll
      for (int tt = 0; tt < 4; ++tt)
#pragma unroll
        for (int r = 0; r < 4; ++r) p[tt * 4 + r] = EXP2F(s[tt][r] - m);
      float ts = 0.f;
#pragma unroll
      for (int i = 0; i < 16; ++i) ts += p[i];
      lp += ts;

      // ---- pack (HW cvt_pk) + redistribute into PV A-frags ----
      int wd[8];
#pragma unroll
      for (int tt = 0; tt < 4; ++tt) {
        wd[tt * 2 + 0] = cvtpk(p[tt * 4 + 0], p[tt * 4 + 1]);
        wd[tt * 2 + 1] = cvtpk(p[tt * 4 + 2], p[tt * 4 + 3]);
      }
      union { int u[4]; u16x8 v; } pu0, pu1;
      pu0.u[0] = glo2 ? __shfl(wd[0], srcA) : __shfl(wd[2], srcA);
      pu0.u[1] = glo2 ? __shfl(wd[1], srcA) : __shfl(wd[3], srcA);
      pu0.u[2] = glo2 ? __shfl(wd[0], srcH) : __shfl(wd[2], srcH);
      pu0.u[3] = glo2 ? __shfl(wd[1], srcH) : __shfl(wd[3], srcH);
      pu1.u[0] = glo2 ? __shfl(wd[4], srcA) : __shfl(wd[6], srcA);
      pu1.u[1] = glo2 ? __shfl(wd[5], srcA) : __shfl(wd[7], srcA);
      pu1.u[2] = glo2 ? __shfl(wd[4], srcH) : __shfl(wd[6], srcH);
      pu1.u[3] = glo2 ? __shfl(wd[5], srcH) : __shfl(wd[7], srcH);

      // ---- PV from LDS (swizzled read) ----
      __builtin_amdgcn_s_setprio(1);
#pragma unroll
      for (int d = 0; d < 4; ++d) {
        const int rowb = (d * 16 + c) * 64;
        const u16x8 v0 = *(const u16x8*)(Vs + rowb + ((g ^ cx)) * 8);
        const u16x8 v1 = *(const u16x8*)(Vs + rowb + (((4 + g) ^ cx)) * 8);
        oacc[d] = mfma16(pu0.v, v0, oacc[d]);
        oacc[d] = mfma16(pu1.v, v1, oacc[d]);
      }
      __builtin_amdgcn_s_setprio(0);
    }
  }

  float lt = lp;
  lt += __shfl_xor(lt, 16);
  lt += __shfl_xor(lt, 32);
  const int b = bh >> 4, h = bh & 15;
#pragma unroll
  for (int r = 0; r < 4; ++r) {
    const float inv = 1.f / __shfl(lt, 4 * g + r);
    const long base = ((long)b * SEQ + q0 + g * 4 + r) * D_MODEL + h * DHEAD;
#pragma unroll
    for (int d = 0; d < 4; ++d) O[base + d * 16 + c] = f2bf(oacc[d][r] * inv);
  }
}

// ============================================================================
// Fused residual + LayerNorm: out = LN(X + Y)*gamma + beta.
// YPART=1: Y = P0 + P1 + ybias (fp32 split-K partials, fixed-order reduce).
// ============================================================================
template <int XF32, int OUTF32, int YPART>
__global__ __launch_bounds__(256) void add_ln(
    const void* __restrict__ X, const bf16_t* __restrict__ Ybf,
    const float* __restrict__ P0, const float* __restrict__ P1,
    const float* __restrict__ ybias,
    const float* __restrict__ gamma, const float* __restrict__ beta,
    void* __restrict__ Out) {
  __shared__ float red[2][4];
  const int tid = threadIdx.x;
  const int lane = tid & 63, w = tid >> 6;
  const long base = (long)blockIdx.x * D_MODEL;

  float xv[4];
  if (XF32) {
    const float4 t = *(const float4*)((const float*)X + base + tid * 4);
    xv[0] = t.x; xv[1] = t.y; xv[2] = t.z; xv[3] = t.w;
  } else {
    const u16x4 t = *(const u16x4*)((const bf16_t*)X + base + tid * 4);
#pragma unroll
    for (int i = 0; i < 4; ++i) xv[i] = bf2f(t[i]);
  }
  float yv[4];
  if (YPART) {
    const float4 p0 = *(const float4*)(P0 + base + tid * 4);
    const float4 p1 = *(const float4*)(P1 + base + tid * 4);
    const float4 bb = *(const float4*)(ybias + tid * 4);
    yv[0] = p0.x + p1.x + bb.x;
    yv[1] = p0.y + p1.y + bb.y;
    yv[2] = p0.z + p1.z + bb.z;
    yv[3] = p0.w + p1.w + bb.w;
  } else {
    const u16x4 t = *(const u16x4*)(Ybf + base + tid * 4);
#pragma unroll
    for (int i = 0; i < 4; ++i) yv[i] = bf2f(t[i]);
  }
  float v[4], s = 0.f, s2 = 0.f;
#pragma unroll
  for (int i = 0; i < 4; ++i) {
    const float t = xv[i] + yv[i];
    v[i] = t;
    s += t;
    s2 += t * t;
  }
#pragma unroll
  for (int off = 32; off; off >>= 1) {
    s += __shfl_xor(s, off);
    s2 += __shfl_xor(s2, off);
  }
  if (lane == 0) { red[0][w] = s; red[1][w] = s2; }
  __syncthreads();
  s = red[0][0] + red[0][1] + red[0][2] + red[0][3];
  s2 = red[1][0] + red[1][1] + red[1][2] + red[1][3];
  const float mu = s * (1.f / D_MODEL);
  const float var = s2 * (1.f / D_MODEL) - mu * mu;
  const float inv = rsqrtf(var + 1e-5f);
  const float4 gv = *(const float4*)(gamma + tid * 4);
  const float4 bv = *(const float4*)(beta + tid * 4);
  const float o0 = (v[0] - mu) * inv * gv.x + bv.x;
  const float o1 = (v[1] - mu) * inv * gv.y + bv.y;
  const float o2 = (v[2] - mu) * inv * gv.z + bv.z;
  const float o3 = (v[3] - mu) * inv * gv.w + bv.w;
  if (OUTF32) {
    float4 ov; ov.x = o0; ov.y = o1; ov.z = o2; ov.w = o3;
    *(float4*)((float*)Out + base + tid * 4) = ov;
  } else {
    u16x4 ov;
    ov[0] = f2bf(o0); ov[1] = f2bf(o1); ov[2] = f2bf(o2); ov[3] = f2bf(o3);
    *(u16x4*)((bf16_t*)Out + base + tid * 4) = ov;
  }
}

// ============================================================================
extern "C" void kernel_launch(void* const* d_in, const int* in_sizes, int n_in,
                              void* d_out, int out_size, void* d_ws, size_t ws_size,
                              hipStream_t stream) {
  const float* src = (const float*)d_in[0];
  const float* qw = (const float*)d_in[1];
  const float* qb = (const float*)d_in[2];
  const float* kw = (const float*)d_in[3];
  const float* kb = (const float*)d_in[4];
  const float* vw = (const float*)d_in[5];
  const float* vb = (const float*)d_in[6];
  const float* ow = (const float*)d_in[7];
  const float* ob = (const float*)d_in[8];
  const float* w1 = (const float*)d_in[9];
  const float* b1 = (const float*)d_in[10];
  const float* w2 = (const float*)d_in[11];
  const float* b2 = (const float*)d_in[12];
  const float* gam1 = (const float*)d_in[13];
  const float* bet1 = (const float*)d_in[14];
  const float* gam2 = (const float*)d_in[15];
  const float* bet2 = (const float*)d_in[16];

  char* ws = (char*)d_ws;
  const long MB = 1024 * 1024;
  bf16_t* Qw   = (bf16_t*)(ws + 0 * MB);   // 8MB (dead after attn)
  bf16_t* Kw   = (bf16_t*)(ws + 8 * MB);   // 8MB (dead after attn)
  bf16_t* Vt   = (bf16_t*)(ws + 16 * MB);  // 8MB (dead after attn)
  bf16_t* A1   = (bf16_t*)(ws + 24 * MB);  // 8MB (dead after o-proj)
  float*  Po0  = (float*)(ws + 0 * MB);    // o-proj partial0 16MB (over Qw/Kw)
  float*  Po1  = (float*)(ws + 80 * MB);   // o-proj partial1 16MB
  bf16_t* X1   = (bf16_t*)(ws + 40 * MB);  // post-LN1 8MB
  bf16_t* srcB = (bf16_t*)(ws + 48 * MB);  // bf16 src 8MB (dead after QKV)
  bf16_t* Wqkv = (bf16_t*)(ws + 56 * MB);  // 6MB (dead after QKV)
  bf16_t* OWb  = (bf16_t*)(ws + 62 * MB);  // 2MB (dead after o-proj)
  bf16_t* W1b  = (bf16_t*)(ws + 64 * MB);  // 8MB (dead after FF1)
  bf16_t* W2b  = (bf16_t*)(ws + 72 * MB);  // 8MB
  bf16_t* F1   = (bf16_t*)(ws + 0 * MB);   // ff1 32MB (over Po0/Qw..A1)
  float*  P0   = (float*)(ws + 48 * MB);   // ff2 partial0 16MB
  float*  P1   = (float*)(ws + 80 * MB);   // ff2 partial1 16MB

  const int M = BATCH * SEQ;  // 4096
  dim3 blk(256);
  const float qscale = 0.125f * LOG2E;
  const long n1M = 1024 * 1024;

  cvt_f32_bf16<<<dim3(2048), blk, 0, stream>>>(src, srcB, (long)M * D_MODEL);
  cvt_f32_bf16<<<dim3(512), blk, 0, stream>>>(qw, Wqkv, n1M);
  cvt_f32_bf16<<<dim3(512), blk, 0, stream>>>(kw, Wqkv + n1M, n1M);
  cvt_f32_bf16<<<dim3(512), blk, 0, stream>>>(vw, Wqkv + 2 * n1M, n1M);
  cvt_f32_bf16<<<dim3(512), blk, 0, stream>>>(ow, OWb, n1M);
  cvt_f32_bf16<<<dim3(2048), blk, 0, stream>>>(w1, W1b, 4 * n1M);
  cvt_f32_bf16<<<dim3(2048), blk, 0, stream>>>(w2, W2b, 4 * n1M);

  gemm_lds<128, 3><<<dim3(24, 32, 1), blk, 0, stream>>>(
      srcB, Wqkv, qb, kb, vb, Qw, Kw, Vt, (float*)0, (float*)0,
      M, 3072, 1024, 1024, 1024, 0, qscale);
  attn_fwd<<<dim3(1024), blk, 0, stream>>>(Qw, Kw, Vt, A1);
  gemm_lds<128, 4><<<dim3(8, 32, 2), blk, 0, stream>>>(
      A1, OWb, ob, ob, ob, (bf16_t*)0, (bf16_t*)0, (bf16_t*)0, Po0, Po1,
      M, 1024, 512, 1024, 1024, 0, 1.f);
  add_ln<1, 0, 1><<<dim3(M), blk, 0, stream>>>(
      src, (const bf16_t*)0, Po0, Po1, ob, gam1, bet1, X1);
  gemm_lds<128, 0><<<dim3(32, 32, 1), blk, 0, stream>>>(
      X1, W1b, b1, b1, b1, F1, F1, F1, (float*)0, (float*)0,
      M, 4096, 1024, 1024, 1024, 1, 1.f);
  gemm_lds<128, 4><<<dim3(8, 32, 2), blk, 0, stream>>>(
      F1, W2b, b2, b2, b2, (bf16_t*)0, (bf16_t*)0, (bf16_t*)0, P0, P1,
      M, 1024, 2048, 4096, 4096, 0, 1.f);
  add_ln<0, 1, 1><<<dim3(M), blk, 0, stream>>>(
      X1, (const bf16_t*)0, P0, P1, b2, gam2, bet2, d_out);
}

// Round 10
// 280.235 us; speedup vs baseline: 2.0683x; 1.0588x over previous
//
#include <hip/hip_runtime.h>

// ---- raw bf16 bits as unsigned short ----
typedef unsigned short bf16_t;
typedef unsigned short u16x8 __attribute__((ext_vector_type(8)));
typedef unsigned short u16x4 __attribute__((ext_vector_type(4)));
typedef float f32x4 __attribute__((ext_vector_type(4)));

#define D_MODEL 1024
#define NHEAD 16
#define DHEAD 64
#define FF_DIM 4096
#define SEQ 2048
#define BATCH 2
#define LOG2E 1.44269504088896340736f
#define EXP2F(x) __builtin_amdgcn_exp2f(x)

#define GLOAD_LDS16(gp, lp)                                          \
  __builtin_amdgcn_global_load_lds(                                  \
      (const __attribute__((address_space(1))) void*)(gp),           \
      (__attribute__((address_space(3))) void*)(lp), 16, 0, 0)

static __device__ __forceinline__ float bf2f(bf16_t b) {
  union { unsigned u; float f; } x;
  x.u = ((unsigned)b) << 16;
  return x.f;
}
static __device__ __forceinline__ bf16_t f2bf(float f) {
  union { float f; unsigned u; } x;
  x.f = f;
  unsigned r = (x.u + 0x7fffu + ((x.u >> 16) & 1u)) >> 16;
  return (bf16_t)r;
}
// HW packed f32->bf16 (RNE), 1 instruction for 2 values [T12 recipe]
static __device__ __forceinline__ int cvtpk(float lo, float hi) {
  int r;
  asm("v_cvt_pk_bf16_f32 %0, %1, %2" : "=v"(r) : "v"(lo), "v"(hi));
  return r;
}
static __device__ __forceinline__ f32x4 mfma16(u16x8 a, u16x8 b, f32x4 c) {
  return __builtin_amdgcn_mfma_f32_16x16x32_bf16(a, b, c, 0, 0, 0);
}
static __device__ __forceinline__ u16x8 load8_f32(const float* q) {
  const float4 v0 = *(const float4*)(q);
  const float4 v1 = *(const float4*)(q + 4);
  u16x8 r;
  r[0] = f2bf(v0.x); r[1] = f2bf(v0.y); r[2] = f2bf(v0.z); r[3] = f2bf(v0.w);
  r[4] = f2bf(v1.x); r[5] = f2bf(v1.y); r[6] = f2bf(v1.z); r[7] = f2bf(v1.w);
  return r;
}

// ============================================================================
// fp32 -> bf16 bulk convert (n multiple of 2048)
// ============================================================================
__global__ __launch_bounds__(256) void cvt_f32_bf16(
    const float* __restrict__ in, bf16_t* __restrict__ out, long n) {
  const long i = ((long)blockIdx.x * 256 + threadIdx.x) * 8;
  if (i < n) *(u16x8*)(out + i) = load8_f32(in + i);
}

// ============================================================================
// m97-structure GEMM over a K-segment: operands bf16, bias fp32.
// BM x 128 tile, BK=32, global_load_lds width-16, linear LDS.
// SMODE 0: C0[M,N] = act(.+bias)        (grid.z == 1)
// SMODE 3: fused QKV (N=3072): seg0 -> Q * qscale; seg1 -> K; seg2 -> V^T
// SMODE 4: split-K fp32 partials: (z ? CP1 : CP0)[mm*N+nn]
// ============================================================================
template <int BM, int SMODE>
__global__ __launch_bounds__(256) void gemm_lds(
    const bf16_t* __restrict__ A, const bf16_t* __restrict__ W,
    const float* __restrict__ bq_, const float* __restrict__ bk_,
    const float* __restrict__ bv_, bf16_t* __restrict__ C0,
    bf16_t* __restrict__ C1, bf16_t* __restrict__ C2,
    float* __restrict__ CP0, float* __restrict__ CP1,
    int M, int N, int Kseg, long lda, long ldw, int relu, float qscale) {
  constexpr int WM = BM / 2;   // wave tile rows
  constexpr int MI = WM / 16;  // acc row-frags
  __shared__ bf16_t As[BM * 32];
  __shared__ bf16_t Bs[128 * 32];
  const int tid = threadIdx.x;
  const int lane = tid & 63;
  const int w = tid >> 6;
  const int wr = w >> 1, wc = w & 1;
  const int g = lane >> 4, c = lane & 15;
  const long bm = (long)blockIdx.y * BM;
  const long bn = (long)blockIdx.x * 128;
  const long koff = (long)blockIdx.z * Kseg;

  f32x4 acc[MI][4];
#pragma unroll
  for (int i = 0; i < MI; ++i)
#pragma unroll
    for (int j = 0; j < 4; ++j) acc[i][j] = (f32x4){0.f, 0.f, 0.f, 0.f};

  for (int k0 = 0; k0 < Kseg; k0 += 32) {
    __syncthreads();
#pragma unroll
    for (int ld = 0; ld < BM / 64; ++ld) {
      const int ch = ld * 256 + tid;
      GLOAD_LDS16(A + (bm + (ch >> 2)) * lda + koff + k0 + (ch & 3) * 8,
                  As + (ld * 256 + w * 64) * 8);
    }
#pragma unroll
    for (int ld = 0; ld < 2; ++ld) {
      const int ch = ld * 256 + tid;
      GLOAD_LDS16(W + (bn + (ch >> 2)) * ldw + koff + k0 + (ch & 3) * 8,
                  Bs + (ld * 256 + w * 64) * 8);
    }
    __syncthreads();
    u16x8 af[MI], bfv[4];
#pragma unroll
    for (int i = 0; i < MI; ++i)
      af[i] = *(const u16x8*)(As + (wr * WM + i * 16 + c) * 32 + g * 8);
#pragma unroll
    for (int j = 0; j < 4; ++j)
      bfv[j] = *(const u16x8*)(Bs + (wc * 64 + j * 16 + c) * 32 + g * 8);
    __builtin_amdgcn_s_setprio(1);
#pragma unroll
    for (int i = 0; i < MI; ++i)
#pragma unroll
      for (int j = 0; j < 4; ++j) acc[i][j] = mfma16(af[i], bfv[j], acc[i][j]);
    __builtin_amdgcn_s_setprio(0);
  }

  float* __restrict__ cp = blockIdx.z ? CP1 : CP0;
#pragma unroll
  for (int i = 0; i < MI; ++i) {
#pragma unroll
    for (int j = 0; j < 4; ++j) {
      const int nn = (int)bn + wc * 64 + j * 16 + c;
#pragma unroll
      for (int r = 0; r < 4; ++r) {
        const int mm = (int)bm + wr * WM + i * 16 + g * 4 + r;
        if (SMODE == 0) {
          float v = acc[i][j][r] + bq_[nn];
          if (relu) v = fmaxf(v, 0.f);
          C0[(long)mm * N + nn] = f2bf(v);
        } else if (SMODE == 4) {
          cp[(long)mm * N + nn] = acc[i][j][r];
        } else {
          const int seg = nn >> 10;
          const int col = nn & 1023;
          const int h = col >> 6, dh = col & 63;
          const int b = mm >> 11, s = mm & 2047;
          if (seg == 0) {
            const float v = (acc[i][j][r] + bq_[col]) * qscale;
            C0[((((long)b * NHEAD + h) * SEQ + s) << 6) + dh] = f2bf(v);
          } else if (seg == 1) {
            const float v = acc[i][j][r] + bk_[col];
            C1[((((long)b * NHEAD + h) * SEQ + s) << 6) + dh] = f2bf(v);
          } else {
            const float v = acc[i][j][r] + bv_[col];
            C2[(((long)b * NHEAD + h) * DHEAD + dh) * SEQ + s] = f2bf(v);
          }
        }
      }
    }
  }
}

// ============================================================================
// stage a 64x64 bf16 tile into LDS linear [64][64] with per-row chunk XOR
// swizzle. KEY=0: key = row&7 (V tiles). KEY=1: key = (row&3)|((row&8)>>1)
// (K tiles; equals c&7 on the pi-permuted QK read rows).
// ============================================================================
template <int KEY>
static __device__ __forceinline__ void stage_tile(
    const bf16_t* __restrict__ gbase, long rstride, bf16_t* lds,
    int tid, int w) {
#pragma unroll
  for (int i = 0; i < 2; ++i) {
    const int row = i * 32 + (tid >> 3);
    const int key = KEY ? ((row & 3) | ((row & 8) >> 1)) : (row & 7);
    const int c4 = (tid & 7) ^ key;
    GLOAD_LDS16(gbase + (long)row * rstride + c4 * 8,
                lds + (i * 256 + w * 64) * 8);
  }
}

// ============================================================================
// Flash attention: swapped-QK, zero-shuffle PV (pi-permuted K rows so QK
// output lands directly in PV A-frag order), 32 q rows/wave, KVBLK=128,
// cvt_pk pack, defer-max, XCD-aware swizzle. Q pre-scaled by 0.125*log2e.
// Q,K [B*H,S,64]; Vt [B*H,64,S]; all bf16.
// Grid 512 = 8 xcd x (4 heads x 16 q-blocks); block = 4 waves x 32 q.
// Lane (g,c): QK D-rows via pi map -> s[tt][pi][qh][r] = S[t0+tt*32+8g+4*pi+r][q0+qh*16+c].
// ============================================================================
__global__ __launch_bounds__(256, 2) void attn_fwd(
    const bf16_t* __restrict__ Q, const bf16_t* __restrict__ K,
    const bf16_t* __restrict__ Vt, bf16_t* __restrict__ O) {
  __shared__ bf16_t Ks0[64 * 64];
  __shared__ bf16_t Ks1[64 * 64];
  __shared__ bf16_t Vs0[64 * 64];
  __shared__ bf16_t Vs1[64 * 64];
  const int tid = threadIdx.x;
  const int lane = tid & 63;
  const int w = tid >> 6;
  const int g = lane >> 4, c = lane & 15;
  const int lb = blockIdx.x;
  const int xcd = lb & 7, sl = lb >> 3;
  const int bh = xcd * 4 + (sl >> 4);
  const int q0 = (sl & 15) * 128 + w * 32;
  const bf16_t* Qb = Q + (long)bh * SEQ * DHEAD;
  const bf16_t* Kb = K + (long)bh * SEQ * DHEAD;
  const bf16_t* Vb = Vt + (long)bh * DHEAD * SEQ;

  // B-operand Q: [qh][k-half]
  u16x8 bq[2][2];
#pragma unroll
  for (int qh = 0; qh < 2; ++qh) {
    bq[qh][0] = *(const u16x8*)(Qb + (q0 + qh * 16 + c) * DHEAD + g * 8);
    bq[qh][1] = *(const u16x8*)(Qb + (q0 + qh * 16 + c) * DHEAD + 32 + g * 8);
  }

  float m0 = -1e30f, m1 = -1e30f, lp0 = 0.f, lp1 = 0.f;
  f32x4 oacc[4][2];  // [d][qh]
#pragma unroll
  for (int d = 0; d < 4; ++d)
#pragma unroll
    for (int qh = 0; qh < 2; ++qh) oacc[d][qh] = (f32x4){0.f, 0.f, 0.f, 0.f};

  const int ck = c & 7;
  const int pr = ((c >> 2) << 3) | (c & 3);  // pi0(c); pi1 = pr + 4

  for (int t0 = 0; t0 < SEQ; t0 += 128) {
    __syncthreads();  // all waves done reading previous tiles
    stage_tile<1>(Kb + (long)t0 * DHEAD, DHEAD, Ks0, tid, w);
    stage_tile<1>(Kb + (long)(t0 + 64) * DHEAD, DHEAD, Ks1, tid, w);
    stage_tile<0>(Vb + t0, SEQ, Vs0, tid, w);
    stage_tile<0>(Vb + t0 + 64, SEQ, Vs1, tid, w);
    __syncthreads();  // loads landed

#pragma unroll
    for (int sub = 0; sub < 2; ++sub) {
      const bf16_t* Ks = sub ? Ks1 : Ks0;
      const bf16_t* Vs = sub ? Vs1 : Vs0;

      // ---- QK^T: A rows pi-permuted so D rows = t = 8g + 4*pi + r ----
      f32x4 s[2][2][2];  // [tt][pi][qh]
#pragma unroll
      for (int tt = 0; tt < 2; ++tt) {
        const int rowA = (tt * 32 + pr) * 64;
        const int rowC = (tt * 32 + pr + 4) * 64;
        const u16x8 kA = *(const u16x8*)(Ks + rowA + (g ^ ck) * 8);
        const u16x8 kB = *(const u16x8*)(Ks + rowA + ((4 + g) ^ ck) * 8);
        const u16x8 kC = *(const u16x8*)(Ks + rowC + (g ^ ck) * 8);
        const u16x8 kD = *(const u16x8*)(Ks + rowC + ((4 + g) ^ ck) * 8);
        __builtin_amdgcn_s_setprio(1);
#pragma unroll
        for (int qh = 0; qh < 2; ++qh) {
          s[tt][0][qh] = mfma16(kA, bq[qh][0], (f32x4){0.f, 0.f, 0.f, 0.f});
          s[tt][0][qh] = mfma16(kB, bq[qh][1], s[tt][0][qh]);
          s[tt][1][qh] = mfma16(kC, bq[qh][0], (f32x4){0.f, 0.f, 0.f, 0.f});
          s[tt][1][qh] = mfma16(kD, bq[qh][1], s[tt][1][qh]);
        }
        __builtin_amdgcn_s_setprio(0);
      }

      // ---- softmax (exp2 domain), defer-max, per q-half ----
      float pmv[2];
#pragma unroll
      for (int qh = 0; qh < 2; ++qh) {
        float pm = s[0][0][qh][0];
#pragma unroll
        for (int tt = 0; tt < 2; ++tt)
#pragma unroll
          for (int pi = 0; pi < 2; ++pi)
#pragma unroll
            for (int r = 0; r < 4; ++r) pm = fmaxf(pm, s[tt][pi][qh][r]);
        pm = fmaxf(pm, __shfl_xor(pm, 16));
        pm = fmaxf(pm, __shfl_xor(pm, 32));
        pmv[qh] = pm;
      }
      if (!__all(pmv[0] <= m0 + 8.f && pmv[1] <= m1 + 8.f)) {
        const float mn0 = fmaxf(m0, pmv[0]);
        const float mn1 = fmaxf(m1, pmv[1]);
        const float f0 = EXP2F(m0 - mn0);
        const float f1 = EXP2F(m1 - mn1);
        m0 = mn0; m1 = mn1;
        lp0 *= f0; lp1 *= f1;
        float fb0[4], fb1[4];
#pragma unroll
        for (int r = 0; r < 4; ++r) {
          fb0[r] = __shfl(f0, 4 * g + r);
          fb1[r] = __shfl(f1, 4 * g + r);
        }
#pragma unroll
        for (int d = 0; d < 4; ++d)
#pragma unroll
          for (int r = 0; r < 4; ++r) {
            oacc[d][0][r] *= fb0[r];
            oacc[d][1][r] *= fb1[r];
          }
      }
      float ts0 = 0.f, ts1 = 0.f;
#pragma unroll
      for (int tt = 0; tt < 2; ++tt)
#pragma unroll
        for (int pi = 0; pi < 2; ++pi)
#pragma unroll
          for (int r = 0; r < 4; ++r) {
            s[tt][pi][0][r] = EXP2F(s[tt][pi][0][r] - m0);
            s[tt][pi][1][r] = EXP2F(s[tt][pi][1][r] - m1);
            ts0 += s[tt][pi][0][r];
            ts1 += s[tt][pi][1][r];
          }
      lp0 += ts0;
      lp1 += ts1;

      // ---- pack: s already in PV A-frag order (t = 8g+0..7 per tt) ----
      union { int u[4]; u16x8 v; } pu[2][2];  // [qh][tt]
#pragma unroll
      for (int qh = 0; qh < 2; ++qh)
#pragma unroll
        for (int tt = 0; tt < 2; ++tt) {
          pu[qh][tt].u[0] = cvtpk(s[tt][0][qh][0], s[tt][0][qh][1]);
          pu[qh][tt].u[1] = cvtpk(s[tt][0][qh][2], s[tt][0][qh][3]);
          pu[qh][tt].u[2] = cvtpk(s[tt][1][qh][0], s[tt][1][qh][1]);
          pu[qh][tt].u[3] = cvtpk(s[tt][1][qh][2], s[tt][1][qh][3]);
        }

      // ---- PV from LDS (swizzled read) ----
#pragma unroll
      for (int d = 0; d < 4; ++d) {
        const int rowb = (d * 16 + c) * 64;
        const u16x8 v0 = *(const u16x8*)(Vs + rowb + ((g ^ ck)) * 8);
        const u16x8 v1 = *(const u16x8*)(Vs + rowb + (((4 + g) ^ ck)) * 8);
        __builtin_amdgcn_s_setprio(1);
        oacc[d][0] = mfma16(pu[0][0].v, v0, oacc[d][0]);
        oacc[d][0] = mfma16(pu[0][1].v, v1, oacc[d][0]);
        oacc[d][1] = mfma16(pu[1][0].v, v0, oacc[d][1]);
        oacc[d][1] = mfma16(pu[1][1].v, v1, oacc[d][1]);
        __builtin_amdgcn_s_setprio(0);
      }
    }
  }

  const int b = bh >> 4, h = bh & 15;
#pragma unroll
  for (int qh = 0; qh < 2; ++qh) {
    float lt = qh ? lp1 : lp0;
    lt += __shfl_xor(lt, 16);
    lt += __shfl_xor(lt, 32);
#pragma unroll
    for (int r = 0; r < 4; ++r) {
      const float inv = 1.f / __shfl(lt, 4 * g + r);
      const long base =
          ((long)b * SEQ + q0 + qh * 16 + g * 4 + r) * D_MODEL + h * DHEAD;
#pragma unroll
      for (int d = 0; d < 4; ++d)
        O[base + d * 16 + c] = f2bf(oacc[d][qh][r] * inv);
    }
  }
}

// ============================================================================
// Fused residual + LayerNorm: out = LN(X + Y)*gamma + beta.
// YPART=1: Y = P0 + P1 + ybias (fp32 split-K partials, fixed-order reduce).
// ============================================================================
template <int XF32, int OUTF32, int YPART>
__global__ __launch_bounds__(256) void add_ln(
    const void* __restrict__ X, const bf16_t* __restrict__ Ybf,
    const float* __restrict__ P0, const float* __restrict__ P1,
    const float* __restrict__ ybias,
    const float* __restrict__ gamma, const float* __restrict__ beta,
    void* __restrict__ Out) {
  __shared__ float red[2][4];
  const int tid = threadIdx.x;
  const int lane = tid & 63, w = tid >> 6;
  const long base = (long)blockIdx.x * D_MODEL;

  float xv[4];
  if (XF32) {
    const float4 t = *(const float4*)((const float*)X + base + tid * 4);
    xv[0] = t.x; xv[1] = t.y; xv[2] = t.z; xv[3] = t.w;
  } else {
    const u16x4 t = *(const u16x4*)((const bf16_t*)X + base + tid * 4);
#pragma unroll
    for (int i = 0; i < 4; ++i) xv[i] = bf2f(t[i]);
  }
  float yv[4];
  if (YPART) {
    const float4 p0 = *(const float4*)(P0 + base + tid * 4);
    const float4 p1 = *(const float4*)(P1 + base + tid * 4);
    const float4 bb = *(const float4*)(ybias + tid * 4);
    yv[0] = p0.x + p1.x + bb.x;
    yv[1] = p0.y + p1.y + bb.y;
    yv[2] = p0.z + p1.z + bb.z;
    yv[3] = p0.w + p1.w + bb.w;
  } else {
    const u16x4 t = *(const u16x4*)(Ybf + base + tid * 4);
#pragma unroll
    for (int i = 0; i < 4; ++i) yv[i] = bf2f(t[i]);
  }
  float v[4], s = 0.f, s2 = 0.f;
#pragma unroll
  for (int i = 0; i < 4; ++i) {
    const float t = xv[i] + yv[i];
    v[i] = t;
    s += t;
    s2 += t * t;
  }
#pragma unroll
  for (int off = 32; off; off >>= 1) {
    s += __shfl_xor(s, off);
    s2 += __shfl_xor(s2, off);
  }
  if (lane == 0) { red[0][w] = s; red[1][w] = s2; }
  __syncthreads();
  s = red[0][0] + red[0][1] + red[0][2] + red[0][3];
  s2 = red[1][0] + red[1][1] + red[1][2] + red[1][3];
  const float mu = s * (1.f / D_MODEL);
  const float var = s2 * (1.f / D_MODEL) - mu * mu;
  const float inv = rsqrtf(var + 1e-5f);
  const float4 gv = *(const float4*)(gamma + tid * 4);
  const float4 bv = *(const float4*)(beta + tid * 4);
  const float o0 = (v[0] - mu) * inv * gv.x + bv.x;
  const float o1 = (v[1] - mu) * inv * gv.y + bv.y;
  const float o2 = (v[2] - mu) * inv * gv.z + bv.z;
  const float o3 = (v[3] - mu) * inv * gv.w + bv.w;
  if (OUTF32) {
    float4 ov; ov.x = o0; ov.y = o1; ov.z = o2; ov.w = o3;
    *(float4*)((float*)Out + base + tid * 4) = ov;
  } else {
    u16x4 ov;
    ov[0] = f2bf(o0); ov[1] = f2bf(o1); ov[2] = f2bf(o2); ov[3] = f2bf(o3);
    *(u16x4*)((bf16_t*)Out + base + tid * 4) = ov;
  }
}

// ============================================================================
extern "C" void kernel_launch(void* const* d_in, const int* in_sizes, int n_in,
                              void* d_out, int out_size, void* d_ws, size_t ws_size,
                              hipStream_t stream) {
  const float* src = (const float*)d_in[0];
  const float* qw = (const float*)d_in[1];
  const float* qb = (const float*)d_in[2];
  const float* kw = (const float*)d_in[3];
  const float* kb = (const float*)d_in[4];
  const float* vw = (const float*)d_in[5];
  const float* vb = (const float*)d_in[6];
  const float* ow = (const float*)d_in[7];
  const float* ob = (const float*)d_in[8];
  const float* w1 = (const float*)d_in[9];
  const float* b1 = (const float*)d_in[10];
  const float* w2 = (const float*)d_in[11];
  const float* b2 = (const float*)d_in[12];
  const float* gam1 = (const float*)d_in[13];
  const float* bet1 = (const float*)d_in[14];
  const float* gam2 = (const float*)d_in[15];
  const float* bet2 = (const float*)d_in[16];

  char* ws = (char*)d_ws;
  const long MB = 1024 * 1024;
  bf16_t* Qw   = (bf16_t*)(ws + 0 * MB);   // 8MB (dead after attn)
  bf16_t* Kw   = (bf16_t*)(ws + 8 * MB);   // 8MB (dead after attn)
  bf16_t* Vt   = (bf16_t*)(ws + 16 * MB);  // 8MB (dead after attn)
  bf16_t* A1   = (bf16_t*)(ws + 24 * MB);  // 8MB (dead after o-proj)
  float*  Po0  = (float*)(ws + 0 * MB);    // o-proj partial0 16MB (over Qw/Kw)
  float*  Po1  = (float*)(ws + 80 * MB);   // o-proj partial1 16MB
  bf16_t* X1   = (bf16_t*)(ws + 40 * MB);  // post-LN1 8MB
  bf16_t* srcB = (bf16_t*)(ws + 48 * MB);  // bf16 src 8MB (dead after QKV)
  bf16_t* Wqkv = (bf16_t*)(ws + 56 * MB);  // 6MB (dead after QKV)
  bf16_t* OWb  = (bf16_t*)(ws + 62 * MB);  // 2MB (dead after o-proj)
  bf16_t* W1b  = (bf16_t*)(ws + 64 * MB);  // 8MB (dead after FF1)
  bf16_t* W2b  = (bf16_t*)(ws + 72 * MB);  // 8MB
  bf16_t* F1   = (bf16_t*)(ws + 0 * MB);   // ff1 32MB (over Po0/Qw..A1)
  float*  P0   = (float*)(ws + 48 * MB);   // ff2 partial0 16MB
  float*  P1   = (float*)(ws + 80 * MB);   // ff2 partial1 16MB

  const int M = BATCH * SEQ;  // 4096
  dim3 blk(256);
  const float qscale = 0.125f * LOG2E;
  const long n1M = 1024 * 1024;

  cvt_f32_bf16<<<dim3(2048), blk, 0, stream>>>(src, srcB, (long)M * D_MODEL);
  cvt_f32_bf16<<<dim3(512), blk, 0, stream>>>(qw, Wqkv, n1M);
  cvt_f32_bf16<<<dim3(512), blk, 0, stream>>>(kw, Wqkv + n1M, n1M);
  cvt_f32_bf16<<<dim3(512), blk, 0, stream>>>(vw, Wqkv + 2 * n1M, n1M);
  cvt_f32_bf16<<<dim3(512), blk, 0, stream>>>(ow, OWb, n1M);
  cvt_f32_bf16<<<dim3(2048), blk, 0, stream>>>(w1, W1b, 4 * n1M);
  cvt_f32_bf16<<<dim3(2048), blk, 0, stream>>>(w2, W2b, 4 * n1M);

  gemm_lds<128, 3><<<dim3(24, 32, 1), blk, 0, stream>>>(
      srcB, Wqkv, qb, kb, vb, Qw, Kw, Vt, (float*)0, (float*)0,
      M, 3072, 1024, 1024, 1024, 0, qscale);
  attn_fwd<<<dim3(512), blk, 0, stream>>>(Qw, Kw, Vt, A1);
  gemm_lds<128, 4><<<dim3(8, 32, 2), blk, 0, stream>>>(
      A1, OWb, ob, ob, ob, (bf16_t*)0, (bf16_t*)0, (bf16_t*)0, Po0, Po1,
      M, 1024, 512, 1024, 1024, 0, 1.f);
  add_ln<1, 0, 1><<<dim3(M), blk, 0, stream>>>(
      src, (const bf16_t*)0, Po0, Po1, ob, gam1, bet1, X1);
  gemm_lds<128, 0><<<dim3(32, 32, 1), blk, 0, stream>>>(
      X1, W1b, b1, b1, b1, F1, F1, F1, (float*)0, (float*)0,
      M, 4096, 1024, 1024, 1024, 1, 1.f);
  gemm_lds<128, 4><<<dim3(8, 32, 2), blk, 0, stream>>>(
      F1, W2b, b2, b2, b2, (bf16_t*)0, (bf16_t*)0, (bf16_t*)0, P0, P1,
      M, 1024, 2048, 4096, 4096, 0, 1.f);
  add_ln<0, 1, 1><<<dim3(M), blk, 0, stream>>>(
      X1, (const bf16_t*)0, P0, P1, b2, gam2, bet2, d_out);
}

// Round 11
// 271.785 us; speedup vs baseline: 2.1326x; 1.0311x over previous
//
#include <hip/hip_runtime.h>

// ---- raw bf16 bits as unsigned short ----
typedef unsigned short bf16_t;
typedef unsigned short u16x8 __attribute__((ext_vector_type(8)));
typedef unsigned short u16x4 __attribute__((ext_vector_type(4)));
typedef float f32x4 __attribute__((ext_vector_type(4)));

#define D_MODEL 1024
#define NHEAD 16
#define DHEAD 64
#define FF_DIM 4096
#define SEQ 2048
#define BATCH 2
#define LOG2E 1.44269504088896340736f
#define EXP2F(x) __builtin_amdgcn_exp2f(x)

#define GLOAD_LDS16(gp, lp)                                          \
  __builtin_amdgcn_global_load_lds(                                  \
      (const __attribute__((address_space(1))) void*)(gp),           \
      (__attribute__((address_space(3))) void*)(lp), 16, 0, 0)

static __device__ __forceinline__ float bf2f(bf16_t b) {
  union { unsigned u; float f; } x;
  x.u = ((unsigned)b) << 16;
  return x.f;
}
static __device__ __forceinline__ bf16_t f2bf(float f) {
  union { float f; unsigned u; } x;
  x.f = f;
  unsigned r = (x.u + 0x7fffu + ((x.u >> 16) & 1u)) >> 16;
  return (bf16_t)r;
}
// HW packed f32->bf16 (RNE), 1 instruction for 2 values [T12 recipe]
static __device__ __forceinline__ int cvtpk(float lo, float hi) {
  int r;
  asm("v_cvt_pk_bf16_f32 %0, %1, %2" : "=v"(r) : "v"(lo), "v"(hi));
  return r;
}
static __device__ __forceinline__ f32x4 mfma16(u16x8 a, u16x8 b, f32x4 c) {
  return __builtin_amdgcn_mfma_f32_16x16x32_bf16(a, b, c, 0, 0, 0);
}
static __device__ __forceinline__ u16x8 load8_f32(const float* q) {
  const float4 v0 = *(const float4*)(q);
  const float4 v1 = *(const float4*)(q + 4);
  u16x8 r;
  r[0] = f2bf(v0.x); r[1] = f2bf(v0.y); r[2] = f2bf(v0.z); r[3] = f2bf(v0.w);
  r[4] = f2bf(v1.x); r[5] = f2bf(v1.y); r[6] = f2bf(v1.z); r[7] = f2bf(v1.w);
  return r;
}

// ============================================================================
// fp32 -> bf16 bulk convert (n multiple of 2048)
// ============================================================================
__global__ __launch_bounds__(256) void cvt_f32_bf16(
    const float* __restrict__ in, bf16_t* __restrict__ out, long n) {
  const long i = ((long)blockIdx.x * 256 + threadIdx.x) * 8;
  if (i < n) *(u16x8*)(out + i) = load8_f32(in + i);
}

// ============================================================================
// m97-structure GEMM over a K-segment: operands bf16, bias fp32.
// 128x128 tile, BK=32, global_load_lds width-16, linear LDS.
// 1D grid with XCD-chunked supertile decode: hw block lb -> xcd = lb&7,
// tile = xcd*(T/8) + lb>>3; tiles ordered in 4(bm) x 8(bn) supertiles so each
// XCD's concurrently-resident blocks share ~3MB of panels (fits 4MB L2).
// SMODE 0: C0[M,N] = act(.+bias)
// SMODE 3: fused QKV (N=3072): seg0 -> Q * qscale; seg1 -> K; seg2 -> V^T
// SMODE 4: split-K fp32 partials: (z ? CP1 : CP0)[mm*N+nn]
// ============================================================================
template <int SMODE>
__global__ __launch_bounds__(256) void gemm_lds(
    const bf16_t* __restrict__ A, const bf16_t* __restrict__ W,
    const float* __restrict__ bq_, const float* __restrict__ bk_,
    const float* __restrict__ bv_, bf16_t* __restrict__ C0,
    bf16_t* __restrict__ C1, bf16_t* __restrict__ C2,
    float* __restrict__ CP0, float* __restrict__ CP1,
    int N, int Kseg, long lda, long ldw, int relu, float qscale,
    int gxs) {  // gxs = (N-tiles)/8
  __shared__ bf16_t As[128 * 32];
  __shared__ bf16_t Bs[128 * 32];
  const int tid = threadIdx.x;
  const int lane = tid & 63;
  const int w = tid >> 6;
  const int wr = w >> 1, wc = w & 1;
  const int g = lane >> 4, c = lane & 15;

  // XCD-chunk + supertile decode
  const int per = (int)gridDim.x >> 3;
  const int gt = (blockIdx.x & 7) * per + (blockIdx.x >> 3);
  const int u = gt & 31;          // within 4x8 supertile
  const int st = gt >> 5;         // supertile id
  const int sx = st % gxs;
  const int t2 = st / gxs;
  const int sy = t2 & 7;          // gy/4 == 8 always (gy == 32)
  const int z = t2 >> 3;
  const long bm = (long)(sy * 4 + (u & 3)) * 128;
  const long bn = (long)(sx * 8 + (u >> 2)) * 128;
  const long koff = (long)z * Kseg;

  f32x4 acc[4][4];
#pragma unroll
  for (int i = 0; i < 4; ++i)
#pragma unroll
    for (int j = 0; j < 4; ++j) acc[i][j] = (f32x4){0.f, 0.f, 0.f, 0.f};

  for (int k0 = 0; k0 < Kseg; k0 += 32) {
    __syncthreads();
#pragma unroll
    for (int ld = 0; ld < 2; ++ld) {
      const int ch = ld * 256 + tid;
      GLOAD_LDS16(A + (bm + (ch >> 2)) * lda + koff + k0 + (ch & 3) * 8,
                  As + (ld * 256 + w * 64) * 8);
    }
#pragma unroll
    for (int ld = 0; ld < 2; ++ld) {
      const int ch = ld * 256 + tid;
      GLOAD_LDS16(W + (bn + (ch >> 2)) * ldw + koff + k0 + (ch & 3) * 8,
                  Bs + (ld * 256 + w * 64) * 8);
    }
    __syncthreads();
    u16x8 af[4], bfv[4];
#pragma unroll
    for (int i = 0; i < 4; ++i)
      af[i] = *(const u16x8*)(As + (wr * 64 + i * 16 + c) * 32 + g * 8);
#pragma unroll
    for (int j = 0; j < 4; ++j)
      bfv[j] = *(const u16x8*)(Bs + (wc * 64 + j * 16 + c) * 32 + g * 8);
    __builtin_amdgcn_s_setprio(1);
#pragma unroll
    for (int i = 0; i < 4; ++i)
#pragma unroll
      for (int j = 0; j < 4; ++j) acc[i][j] = mfma16(af[i], bfv[j], acc[i][j]);
    __builtin_amdgcn_s_setprio(0);
  }

  float* __restrict__ cp = z ? CP1 : CP0;
#pragma unroll
  for (int i = 0; i < 4; ++i) {
#pragma unroll
    for (int j = 0; j < 4; ++j) {
      const int nn = (int)bn + wc * 64 + j * 16 + c;
#pragma unroll
      for (int r = 0; r < 4; ++r) {
        const int mm = (int)bm + wr * 64 + i * 16 + g * 4 + r;
        if (SMODE == 0) {
          float v = acc[i][j][r] + bq_[nn];
          if (relu) v = fmaxf(v, 0.f);
          C0[(long)mm * N + nn] = f2bf(v);
        } else if (SMODE == 4) {
          cp[(long)mm * N + nn] = acc[i][j][r];
        } else {
          const int seg = nn >> 10;
          const int col = nn & 1023;
          const int h = col >> 6, dh = col & 63;
          const int b = mm >> 11, s = mm & 2047;
          if (seg == 0) {
            const float v = (acc[i][j][r] + bq_[col]) * qscale;
            C0[((((long)b * NHEAD + h) * SEQ + s) << 6) + dh] = f2bf(v);
          } else if (seg == 1) {
            const float v = acc[i][j][r] + bk_[col];
            C1[((((long)b * NHEAD + h) * SEQ + s) << 6) + dh] = f2bf(v);
          } else {
            const float v = acc[i][j][r] + bv_[col];
            C2[(((long)b * NHEAD + h) * DHEAD + dh) * SEQ + s] = f2bf(v);
          }
        }
      }
    }
  }
}

// ============================================================================
// stage a 64x64 bf16 tile into LDS linear [64][64] with per-row chunk XOR
// swizzle. KEY=0: key = row&7 (V tiles). KEY=1: key = (row&3)|((row&8)>>1)
// (K tiles; equals c&7 on the pi-permuted QK read rows).
// ============================================================================
template <int KEY>
static __device__ __forceinline__ void stage_tile(
    const bf16_t* __restrict__ gbase, long rstride, bf16_t* lds,
    int tid, int w) {
#pragma unroll
  for (int i = 0; i < 2; ++i) {
    const int row = i * 32 + (tid >> 3);
    const int key = KEY ? ((row & 3) | ((row & 8) >> 1)) : (row & 7);
    const int c4 = (tid & 7) ^ key;
    GLOAD_LDS16(gbase + (long)row * rstride + c4 * 8,
                lds + (i * 256 + w * 64) * 8);
  }
}

// ============================================================================
// Flash attention: swapped-QK, zero-shuffle PV (pi-permuted K rows so QK
// output lands directly in PV A-frag order), 32 q rows/wave, KVBLK=128,
// cvt_pk pack, defer-max, XCD-aware swizzle. Q pre-scaled by 0.125*log2e.
// ============================================================================
__global__ __launch_bounds__(256, 2) void attn_fwd(
    const bf16_t* __restrict__ Q, const bf16_t* __restrict__ K,
    const bf16_t* __restrict__ Vt, bf16_t* __restrict__ O) {
  __shared__ bf16_t Ks0[64 * 64];
  __shared__ bf16_t Ks1[64 * 64];
  __shared__ bf16_t Vs0[64 * 64];
  __shared__ bf16_t Vs1[64 * 64];
  const int tid = threadIdx.x;
  const int lane = tid & 63;
  const int w = tid >> 6;
  const int g = lane >> 4, c = lane & 15;
  const int lb = blockIdx.x;
  const int xcd = lb & 7, sl = lb >> 3;
  const int bh = xcd * 4 + (sl >> 4);
  const int q0 = (sl & 15) * 128 + w * 32;
  const bf16_t* Qb = Q + (long)bh * SEQ * DHEAD;
  const bf16_t* Kb = K + (long)bh * SEQ * DHEAD;
  const bf16_t* Vb = Vt + (long)bh * DHEAD * SEQ;

  u16x8 bq[2][2];
#pragma unroll
  for (int qh = 0; qh < 2; ++qh) {
    bq[qh][0] = *(const u16x8*)(Qb + (q0 + qh * 16 + c) * DHEAD + g * 8);
    bq[qh][1] = *(const u16x8*)(Qb + (q0 + qh * 16 + c) * DHEAD + 32 + g * 8);
  }

  float m0 = -1e30f, m1 = -1e30f, lp0 = 0.f, lp1 = 0.f;
  f32x4 oacc[4][2];  // [d][qh]
#pragma unroll
  for (int d = 0; d < 4; ++d)
#pragma unroll
    for (int qh = 0; qh < 2; ++qh) oacc[d][qh] = (f32x4){0.f, 0.f, 0.f, 0.f};

  const int ck = c & 7;
  const int pr = ((c >> 2) << 3) | (c & 3);  // pi0(c); pi1 = pr + 4

  for (int t0 = 0; t0 < SEQ; t0 += 128) {
    __syncthreads();
    stage_tile<1>(Kb + (long)t0 * DHEAD, DHEAD, Ks0, tid, w);
    stage_tile<1>(Kb + (long)(t0 + 64) * DHEAD, DHEAD, Ks1, tid, w);
    stage_tile<0>(Vb + t0, SEQ, Vs0, tid, w);
    stage_tile<0>(Vb + t0 + 64, SEQ, Vs1, tid, w);
    __syncthreads();

#pragma unroll
    for (int sub = 0; sub < 2; ++sub) {
      const bf16_t* Ks = sub ? Ks1 : Ks0;
      const bf16_t* Vs = sub ? Vs1 : Vs0;

      f32x4 s[2][2][2];  // [tt][pi][qh]
#pragma unroll
      for (int tt = 0; tt < 2; ++tt) {
        const int rowA = (tt * 32 + pr) * 64;
        const int rowC = (tt * 32 + pr + 4) * 64;
        const u16x8 kA = *(const u16x8*)(Ks + rowA + (g ^ ck) * 8);
        const u16x8 kB = *(const u16x8*)(Ks + rowA + ((4 + g) ^ ck) * 8);
        const u16x8 kC = *(const u16x8*)(Ks + rowC + (g ^ ck) * 8);
        const u16x8 kD = *(const u16x8*)(Ks + rowC + ((4 + g) ^ ck) * 8);
        __builtin_amdgcn_s_setprio(1);
#pragma unroll
        for (int qh = 0; qh < 2; ++qh) {
          s[tt][0][qh] = mfma16(kA, bq[qh][0], (f32x4){0.f, 0.f, 0.f, 0.f});
          s[tt][0][qh] = mfma16(kB, bq[qh][1], s[tt][0][qh]);
          s[tt][1][qh] = mfma16(kC, bq[qh][0], (f32x4){0.f, 0.f, 0.f, 0.f});
          s[tt][1][qh] = mfma16(kD, bq[qh][1], s[tt][1][qh]);
        }
        __builtin_amdgcn_s_setprio(0);
      }

      float pmv[2];
#pragma unroll
      for (int qh = 0; qh < 2; ++qh) {
        float pm = s[0][0][qh][0];
#pragma unroll
        for (int tt = 0; tt < 2; ++tt)
#pragma unroll
          for (int pi = 0; pi < 2; ++pi)
#pragma unroll
            for (int r = 0; r < 4; ++r) pm = fmaxf(pm, s[tt][pi][qh][r]);
        pm = fmaxf(pm, __shfl_xor(pm, 16));
        pm = fmaxf(pm, __shfl_xor(pm, 32));
        pmv[qh] = pm;
      }
      if (!__all(pmv[0] <= m0 + 8.f && pmv[1] <= m1 + 8.f)) {
        const float mn0 = fmaxf(m0, pmv[0]);
        const float mn1 = fmaxf(m1, pmv[1]);
        const float f0 = EXP2F(m0 - mn0);
        const float f1 = EXP2F(m1 - mn1);
        m0 = mn0; m1 = mn1;
        lp0 *= f0; lp1 *= f1;
        float fb0[4], fb1[4];
#pragma unroll
        for (int r = 0; r < 4; ++r) {
          fb0[r] = __shfl(f0, 4 * g + r);
          fb1[r] = __shfl(f1, 4 * g + r);
        }
#pragma unroll
        for (int d = 0; d < 4; ++d)
#pragma unroll
          for (int r = 0; r < 4; ++r) {
            oacc[d][0][r] *= fb0[r];
            oacc[d][1][r] *= fb1[r];
          }
      }
      float ts0 = 0.f, ts1 = 0.f;
#pragma unroll
      for (int tt = 0; tt < 2; ++tt)
#pragma unroll
        for (int pi = 0; pi < 2; ++pi)
#pragma unroll
          for (int r = 0; r < 4; ++r) {
            s[tt][pi][0][r] = EXP2F(s[tt][pi][0][r] - m0);
            s[tt][pi][1][r] = EXP2F(s[tt][pi][1][r] - m1);
            ts0 += s[tt][pi][0][r];
            ts1 += s[tt][pi][1][r];
          }
      lp0 += ts0;
      lp1 += ts1;

      union { int u[4]; u16x8 v; } pu[2][2];  // [qh][tt]
#pragma unroll
      for (int qh = 0; qh < 2; ++qh)
#pragma unroll
        for (int tt = 0; tt < 2; ++tt) {
          pu[qh][tt].u[0] = cvtpk(s[tt][0][qh][0], s[tt][0][qh][1]);
          pu[qh][tt].u[1] = cvtpk(s[tt][0][qh][2], s[tt][0][qh][3]);
          pu[qh][tt].u[2] = cvtpk(s[tt][1][qh][0], s[tt][1][qh][1]);
          pu[qh][tt].u[3] = cvtpk(s[tt][1][qh][2], s[tt][1][qh][3]);
        }

#pragma unroll
      for (int d = 0; d < 4; ++d) {
        const int rowb = (d * 16 + c) * 64;
        const u16x8 v0 = *(const u16x8*)(Vs + rowb + ((g ^ ck)) * 8);
        const u16x8 v1 = *(const u16x8*)(Vs + rowb + (((4 + g) ^ ck)) * 8);
        __builtin_amdgcn_s_setprio(1);
        oacc[d][0] = mfma16(pu[0][0].v, v0, oacc[d][0]);
        oacc[d][0] = mfma16(pu[0][1].v, v1, oacc[d][0]);
        oacc[d][1] = mfma16(pu[1][0].v, v0, oacc[d][1]);
        oacc[d][1] = mfma16(pu[1][1].v, v1, oacc[d][1]);
        __builtin_amdgcn_s_setprio(0);
      }
    }
  }

  const int b = bh >> 4, h = bh & 15;
#pragma unroll
  for (int qh = 0; qh < 2; ++qh) {
    float lt = qh ? lp1 : lp0;
    lt += __shfl_xor(lt, 16);
    lt += __shfl_xor(lt, 32);
#pragma unroll
    for (int r = 0; r < 4; ++r) {
      const float inv = 1.f / __shfl(lt, 4 * g + r);
      const long base =
          ((long)b * SEQ + q0 + qh * 16 + g * 4 + r) * D_MODEL + h * DHEAD;
#pragma unroll
      for (int d = 0; d < 4; ++d)
        O[base + d * 16 + c] = f2bf(oacc[d][qh][r] * inv);
    }
  }
}

// ============================================================================
// Fused residual + LayerNorm: out = LN(X + Y)*gamma + beta.
// YPART=1: Y = P0 + P1 + ybias (fp32 split-K partials, fixed-order reduce).
// ============================================================================
template <int XF32, int OUTF32, int YPART>
__global__ __launch_bounds__(256) void add_ln(
    const void* __restrict__ X, const bf16_t* __restrict__ Ybf,
    const float* __restrict__ P0, const float* __restrict__ P1,
    const float* __restrict__ ybias,
    const float* __restrict__ gamma, const float* __restrict__ beta,
    void* __restrict__ Out) {
  __shared__ float red[2][4];
  const int tid = threadIdx.x;
  const int lane = tid & 63, w = tid >> 6;
  const long base = (long)blockIdx.x * D_MODEL;

  float xv[4];
  if (XF32) {
    const float4 t = *(const float4*)((const float*)X + base + tid * 4);
    xv[0] = t.x; xv[1] = t.y; xv[2] = t.z; xv[3] = t.w;
  } else {
    const u16x4 t = *(const u16x4*)((const bf16_t*)X + base + tid * 4);
#pragma unroll
    for (int i = 0; i < 4; ++i) xv[i] = bf2f(t[i]);
  }
  float yv[4];
  if (YPART) {
    const float4 p0 = *(const float4*)(P0 + base + tid * 4);
    const float4 p1 = *(const float4*)(P1 + base + tid * 4);
    const float4 bb = *(const float4*)(ybias + tid * 4);
    yv[0] = p0.x + p1.x + bb.x;
    yv[1] = p0.y + p1.y + bb.y;
    yv[2] = p0.z + p1.z + bb.z;
    yv[3] = p0.w + p1.w + bb.w;
  } else {
    const u16x4 t = *(const u16x4*)(Ybf + base + tid * 4);
#pragma unroll
    for (int i = 0; i < 4; ++i) yv[i] = bf2f(t[i]);
  }
  float v[4], s = 0.f, s2 = 0.f;
#pragma unroll
  for (int i = 0; i < 4; ++i) {
    const float t = xv[i] + yv[i];
    v[i] = t;
    s += t;
    s2 += t * t;
  }
#pragma unroll
  for (int off = 32; off; off >>= 1) {
    s += __shfl_xor(s, off);
    s2 += __shfl_xor(s2, off);
  }
  if (lane == 0) { red[0][w] = s; red[1][w] = s2; }
  __syncthreads();
  s = red[0][0] + red[0][1] + red[0][2] + red[0][3];
  s2 = red[1][0] + red[1][1] + red[1][2] + red[1][3];
  const float mu = s * (1.f / D_MODEL);
  const float var = s2 * (1.f / D_MODEL) - mu * mu;
  const float inv = rsqrtf(var + 1e-5f);
  const float4 gv = *(const float4*)(gamma + tid * 4);
  const float4 bv = *(const float4*)(beta + tid * 4);
  const float o0 = (v[0] - mu) * inv * gv.x + bv.x;
  const float o1 = (v[1] - mu) * inv * gv.y + bv.y;
  const float o2 = (v[2] - mu) * inv * gv.z + bv.z;
  const float o3 = (v[3] - mu) * inv * gv.w + bv.w;
  if (OUTF32) {
    float4 ov; ov.x = o0; ov.y = o1; ov.z = o2; ov.w = o3;
    *(float4*)((float*)Out + base + tid * 4) = ov;
  } else {
    u16x4 ov;
    ov[0] = f2bf(o0); ov[1] = f2bf(o1); ov[2] = f2bf(o2); ov[3] = f2bf(o3);
    *(u16x4*)((bf16_t*)Out + base + tid * 4) = ov;
  }
}

// ============================================================================
extern "C" void kernel_launch(void* const* d_in, const int* in_sizes, int n_in,
                              void* d_out, int out_size, void* d_ws, size_t ws_size,
                              hipStream_t stream) {
  const float* src = (const float*)d_in[0];
  const float* qw = (const float*)d_in[1];
  const float* qb = (const float*)d_in[2];
  const float* kw = (const float*)d_in[3];
  const float* kb = (const float*)d_in[4];
  const float* vw = (const float*)d_in[5];
  const float* vb = (const float*)d_in[6];
  const float* ow = (const float*)d_in[7];
  const float* ob = (const float*)d_in[8];
  const float* w1 = (const float*)d_in[9];
  const float* b1 = (const float*)d_in[10];
  const float* w2 = (const float*)d_in[11];
  const float* b2 = (const float*)d_in[12];
  const float* gam1 = (const float*)d_in[13];
  const float* bet1 = (const float*)d_in[14];
  const float* gam2 = (const float*)d_in[15];
  const float* bet2 = (const float*)d_in[16];

  char* ws = (char*)d_ws;
  const long MB = 1024 * 1024;
  bf16_t* Qw   = (bf16_t*)(ws + 0 * MB);   // 8MB (dead after attn)
  bf16_t* Kw   = (bf16_t*)(ws + 8 * MB);   // 8MB (dead after attn)
  bf16_t* Vt   = (bf16_t*)(ws + 16 * MB);  // 8MB (dead after attn)
  bf16_t* A1   = (bf16_t*)(ws + 24 * MB);  // 8MB (dead after o-proj)
  float*  Po0  = (float*)(ws + 0 * MB);    // o-proj partial0 16MB (over Qw/Kw)
  float*  Po1  = (float*)(ws + 80 * MB);   // o-proj partial1 16MB
  bf16_t* X1   = (bf16_t*)(ws + 40 * MB);  // post-LN1 8MB
  bf16_t* srcB = (bf16_t*)(ws + 48 * MB);  // bf16 src 8MB (dead after QKV)
  bf16_t* Wqkv = (bf16_t*)(ws + 56 * MB);  // 6MB (dead after QKV)
  bf16_t* OWb  = (bf16_t*)(ws + 62 * MB);  // 2MB (dead after o-proj)
  bf16_t* W1b  = (bf16_t*)(ws + 64 * MB);  // 8MB (dead after FF1)
  bf16_t* W2b  = (bf16_t*)(ws + 72 * MB);  // 8MB
  bf16_t* F1   = (bf16_t*)(ws + 0 * MB);   // ff1 32MB (over Po0/Qw..A1)
  float*  P0   = (float*)(ws + 48 * MB);   // ff2 partial0 16MB
  float*  P1   = (float*)(ws + 80 * MB);   // ff2 partial1 16MB

  const int M = BATCH * SEQ;  // 4096
  dim3 blk(256);
  const float qscale = 0.125f * LOG2E;
  const long n1M = 1024 * 1024;

  cvt_f32_bf16<<<dim3(2048), blk, 0, stream>>>(src, srcB, (long)M * D_MODEL);
  cvt_f32_bf16<<<dim3(512), blk, 0, stream>>>(qw, Wqkv, n1M);
  cvt_f32_bf16<<<dim3(512), blk, 0, stream>>>(kw, Wqkv + n1M, n1M);
  cvt_f32_bf16<<<dim3(512), blk, 0, stream>>>(vw, Wqkv + 2 * n1M, n1M);
  cvt_f32_bf16<<<dim3(512), blk, 0, stream>>>(ow, OWb, n1M);
  cvt_f32_bf16<<<dim3(2048), blk, 0, stream>>>(w1, W1b, 4 * n1M);
  cvt_f32_bf16<<<dim3(2048), blk, 0, stream>>>(w2, W2b, 4 * n1M);

  // QKV: N=3072 (24 n-tiles, gxs=3), 768 blocks
  gemm_lds<3><<<dim3(768), blk, 0, stream>>>(
      srcB, Wqkv, qb, kb, vb, Qw, Kw, Vt, (float*)0, (float*)0,
      3072, 1024, 1024, 1024, 0, qscale, 3);
  attn_fwd<<<dim3(512), blk, 0, stream>>>(Qw, Kw, Vt, A1);
  // o-proj: N=1024 (gxs=1), split-K2, 512 blocks
  gemm_lds<4><<<dim3(512), blk, 0, stream>>>(
      A1, OWb, ob, ob, ob, (bf16_t*)0, (bf16_t*)0, (bf16_t*)0, Po0, Po1,
      1024, 512, 1024, 1024, 0, 1.f, 1);
  add_ln<1, 0, 1><<<dim3(M), blk, 0, stream>>>(
      src, (const bf16_t*)0, Po0, Po1, ob, gam1, bet1, X1);
  // FF1: N=4096 (gxs=4), 1024 blocks
  gemm_lds<0><<<dim3(1024), blk, 0, stream>>>(
      X1, W1b, b1, b1, b1, F1, F1, F1, (float*)0, (float*)0,
      4096, 1024, 1024, 1024, 1, 1.f, 4);
  // FF2: N=1024 (gxs=1), split-K2, 512 blocks
  gemm_lds<4><<<dim3(512), blk, 0, stream>>>(
      F1, W2b, b2, b2, b2, (bf16_t*)0, (bf16_t*)0, (bf16_t*)0, P0, P1,
      1024, 2048, 4096, 4096, 0, 1.f, 1);
  add_ln<0, 1, 1><<<dim3(M), blk, 0, stream>>>(
      X1, (const bf16_t*)0, P0, P1, b2, gam2, bet2, d_out);
}